// Round 1
// baseline (6201.455 us; speedup 1.0000x reference)
//
#include <hip/hip_runtime.h>
#include <hip/hip_bf16.h>
#include <math.h>

// ---------------------------------------------------------------------------
// SlotAttentionMod: B=16 N=4096 NS=24 D=512 H=8 DH=64 K=512 R=8 ITERS=3
// Strategy (round 1, correctness-first, all f32):
//  - LN(inputs) -> xhat ; k = xhat@Wk ; v = xhat@Wv  (computed once)
//  - per iter: VQ (i>0), LN, q GEMM, dots GEMM (layout [b][i*8+h][n]),
//    softmax over the 192 slot*head entries per (b,n), weighted-V with the
//    EPS renorm folded in analytically, GRU, LN, FF(+LoRA when i>0)
//  - outputs: slots | attn | idx(as float) | commit | idx(as float)
// ---------------------------------------------------------------------------

#define B_ 16
#define N_ 4096
#define NS_ 24
#define D_ 512
#define H_ 8
#define DH_ 64
#define KC_ 512      // codebook size
#define R_ 8
#define TT_ (NS_*H_) // 192
#define EPS_ 1e-8f

// ---------------- LayerNorm (one block per 512-elem row) -------------------
__global__ __launch_bounds__(128) void ln_kernel(const float* __restrict__ X,
    const float* __restrict__ g, const float* __restrict__ bb,
    float* __restrict__ Y)
{
  int row = blockIdx.x;
  const float* xr = X + (size_t)row * D_;
  int t = threadIdx.x;
  float lv[4];
#pragma unroll
  for (int i = 0; i < 4; ++i) lv[i] = xr[t + 128 * i];
  float s = lv[0] + lv[1] + lv[2] + lv[3];
#pragma unroll
  for (int o = 1; o < 64; o <<= 1) s += __shfl_xor(s, o);
  __shared__ float sh[2], sh2[2];
  if ((t & 63) == 0) sh[t >> 6] = s;
  __syncthreads();
  float mean = (sh[0] + sh[1]) * (1.f / D_);
  float q = 0.f;
#pragma unroll
  for (int i = 0; i < 4; ++i) { float d = lv[i] - mean; q += d * d; }
#pragma unroll
  for (int o = 1; o < 64; o <<= 1) q += __shfl_xor(q, o);
  if ((t & 63) == 0) sh2[t >> 6] = q;
  __syncthreads();
  float var = (sh2[0] + sh2[1]) * (1.f / D_);
  float rstd = 1.0f / sqrtf(var + 1e-5f);
#pragma unroll
  for (int i = 0; i < 4; ++i) {
    int d = t + 128 * i;
    Y[(size_t)row * D_ + d] = (lv[i] - mean) * rstd * g[d] + bb[d];
  }
}

// ---------------- generic 64x64-tile f32 GEMM ------------------------------
// C[M,N] = op(A)[M,K] * B (+bias[n]) (+res[m,n]);  B is [K,N] or (BT) [N,K]
template<bool BT, bool RELU_A, bool ADD_RES>
__global__ __launch_bounds__(256) void gemm64(
    const float* __restrict__ A, const float* __restrict__ B,
    const float* __restrict__ bias, const float* __restrict__ res,
    float* __restrict__ C, int M, int N, int K)
{
  __shared__ float As[16][64 + 1];  // [k][m]
  __shared__ float Bs[16][64 + 1];  // [k][n]
  int tx = threadIdx.x & 15, ty = threadIdx.x >> 4;
  int m0 = blockIdx.y * 64, n0 = blockIdx.x * 64;
  float acc[4][4] = {};
  for (int k0 = 0; k0 < K; k0 += 16) {
    for (int e = threadIdx.x; e < 64 * 16; e += 256) {
      int mm = e >> 4, kk = e & 15;
      float a = A[(size_t)(m0 + mm) * K + k0 + kk];
      if (RELU_A) a = fmaxf(a, 0.f);
      As[kk][mm] = a;
    }
    for (int e = threadIdx.x; e < 64 * 16; e += 256) {
      if (!BT) { int kk = e >> 6, nn = e & 63; Bs[kk][nn] = B[(size_t)(k0 + kk) * N + n0 + nn]; }
      else     { int nn = e >> 4, kk = e & 15; Bs[kk][nn] = B[(size_t)(n0 + nn) * K + k0 + kk]; }
    }
    __syncthreads();
#pragma unroll
    for (int kk = 0; kk < 16; ++kk) {
      float av[4], bv[4];
#pragma unroll
      for (int i = 0; i < 4; ++i) av[i] = As[kk][ty * 4 + i];
#pragma unroll
      for (int j = 0; j < 4; ++j) bv[j] = Bs[kk][tx * 4 + j];
#pragma unroll
      for (int i = 0; i < 4; ++i)
#pragma unroll
        for (int j = 0; j < 4; ++j) acc[i][j] += av[i] * bv[j];
    }
    __syncthreads();
  }
#pragma unroll
  for (int i = 0; i < 4; ++i) {
    int m = m0 + ty * 4 + i;
#pragma unroll
    for (int j = 0; j < 4; ++j) {
      int n = n0 + tx * 4 + j;
      float vv = acc[i][j];
      if (bias) vv += bias[n];
      if (ADD_RES) vv += res[(size_t)m * N + n];
      C[(size_t)m * N + n] = vv;
    }
  }
}

// ---------------- vsum[b,h,dh] = sum_j v[b,j,h,dh] -------------------------
__global__ __launch_bounds__(256) void vsum_kernel(const float* __restrict__ v,
                                                   float* __restrict__ vsum)
{
  int b = blockIdx.x >> 3, h = blockIdx.x & 7;
  int dh = threadIdx.x & 63, w = threadIdx.x >> 6;
  float acc = 0.f;
  for (int j = w * (N_ / 4); j < (w + 1) * (N_ / 4); ++j)
    acc += v[((size_t)b * N_ + j) * D_ + h * 64 + dh];
  __shared__ float sh[4][64];
  sh[w][dh] = acc;
  __syncthreads();
  if (w == 0)
    vsum[(size_t)blockIdx.x * 64 + dh] = sh[0][dh] + sh[1][dh] + sh[2][dh] + sh[3][dh];
}

// ---------------- VQ: argmin_c ||slot - code_c||^2 -------------------------
__global__ __launch_bounds__(256) void vq_kernel(const float* __restrict__ slots,
    const float* __restrict__ cb, int* __restrict__ idx, float* __restrict__ commit)
{
  __shared__ float ss[D_];
  int slot = blockIdx.x;
  const float* sr = slots + (size_t)slot * D_;
  for (int d = threadIdx.x; d < D_; d += 256) ss[d] = sr[d];
  __syncthreads();
  float best = 1e30f; int bi = 0;
  for (int c = threadIdx.x; c < KC_; c += 256) {
    const float* cr = cb + (size_t)c * D_;
    float d2 = 0.f;
    for (int d = 0; d < D_; ++d) { float df = ss[d] - cr[d]; d2 += df * df; }
    if (d2 < best) { best = d2; bi = c; }
  }
  __shared__ float rb[256]; __shared__ int ri[256];
  rb[threadIdx.x] = best; ri[threadIdx.x] = bi;
  __syncthreads();
  for (int s = 128; s > 0; s >>= 1) {
    if (threadIdx.x < s) {
      float ob = rb[threadIdx.x + s]; int oi = ri[threadIdx.x + s];
      if (ob < rb[threadIdx.x] || (ob == rb[threadIdx.x] && oi < ri[threadIdx.x])) {
        rb[threadIdx.x] = ob; ri[threadIdx.x] = oi;
      }
    }
    __syncthreads();
  }
  if (threadIdx.x == 0) {
    idx[slot] = ri[0];
    atomicAdd(commit, rb[0] * (1.f / (B_ * NS_ * D_)));
  }
}

// ---------------- dots[b, i*8+h, j] = (q_i . k_j) * 0.125 ------------------
__global__ __launch_bounds__(256) void dots_kernel(const float* __restrict__ q,
    const float* __restrict__ k, float* __restrict__ dots)
{
  int b = blockIdx.y >> 3, h = blockIdx.y & 7;
  int j0 = blockIdx.x * 64;
  __shared__ float qs[NS_][DH_];
  __shared__ float ks[64][DH_ + 1];
  for (int e = threadIdx.x; e < NS_ * DH_; e += 256) {
    int i = e >> 6, dh = e & 63;
    qs[i][dh] = q[(size_t)(b * NS_ + i) * D_ + h * 64 + dh];
  }
  for (int e = threadIdx.x; e < 64 * 64; e += 256) {
    int jj = e >> 6, dh = e & 63;
    ks[jj][dh] = k[((size_t)b * N_ + j0 + jj) * D_ + h * 64 + dh];
  }
  __syncthreads();
  int jj = threadIdx.x & 63;
  int ib = threadIdx.x >> 6;
  float acc[6] = {0.f, 0.f, 0.f, 0.f, 0.f, 0.f};
  for (int dh = 0; dh < 64; ++dh) {
    float kv = ks[jj][dh];
#pragma unroll
    for (int ii = 0; ii < 6; ++ii) acc[ii] += qs[ii * 4 + ib][dh] * kv;
  }
#pragma unroll
  for (int ii = 0; ii < 6; ++ii) {
    int i = ii * 4 + ib;
    dots[((size_t)(b * NS_ + i) * H_ + h) * N_ + j0 + jj] = acc[ii] * 0.125f;
  }
}

// ---------------- softmax over the 192 (slot,head) per (b,j) ---------------
// overwrites dots with softmax weights; accumulates asum[b,t]; writes attn
__global__ __launch_bounds__(256) void softmax_kernel(float* __restrict__ dots,
    float* __restrict__ asum, float* __restrict__ attn)
{
  int b = blockIdx.y;
  int j = blockIdx.x * 256 + threadIdx.x;
  size_t base = (size_t)b * TT_ * N_ + j;
  float m = -1e30f;
  for (int t = 0; t < TT_; ++t) m = fmaxf(m, dots[base + (size_t)t * N_]);
  float S = 0.f;
  for (int t = 0; t < TT_; ++t) S += __expf(dots[base + (size_t)t * N_] - m);
  float rinv = 1.f / S;
  float am[NS_];
#pragma unroll
  for (int i = 0; i < NS_; ++i) am[i] = 0.f;
  for (int t = 0; t < TT_; ++t) {
    float w = __expf(dots[base + (size_t)t * N_] - m) * rinv;
    dots[base + (size_t)t * N_] = w;
    am[t >> 3] += w;
    float wsum = w;
#pragma unroll
    for (int o = 1; o < 64; o <<= 1) wsum += __shfl_xor(wsum, o);
    if ((threadIdx.x & 63) == 0) atomicAdd(&asum[b * TT_ + t], wsum);
  }
  if (attn) {
    for (int i = 0; i < NS_; ++i)
      attn[((size_t)b * NS_ + i) * N_ + j] = am[i] * (1.f / H_);
  }
}

// ---------------- upd[b,i,h,:] = (sum_j a*v + EPS*vsum)/(asum + N*EPS) -----
__global__ __launch_bounds__(256) void upd_kernel(const float* __restrict__ a,
    const float* __restrict__ v, const float* __restrict__ vsum,
    const float* __restrict__ asum, float* __restrict__ upd)
{
  int b = blockIdx.x >> 3, h = blockIdx.x & 7;
  __shared__ float vs[64][DH_ + 1];
  __shared__ float as[NS_][64];
  int dh = threadIdx.x & 63;
  int ib = threadIdx.x >> 6;
  float acc[6] = {0.f, 0.f, 0.f, 0.f, 0.f, 0.f};
  for (int j0 = 0; j0 < N_; j0 += 64) {
    __syncthreads();
    for (int e = threadIdx.x; e < 64 * 64; e += 256) {
      int jj = e >> 6, d2 = e & 63;
      vs[jj][d2] = v[((size_t)b * N_ + j0 + jj) * D_ + h * 64 + d2];
    }
    for (int e = threadIdx.x; e < NS_ * 64; e += 256) {
      int i = e >> 6, jj = e & 63;
      as[i][jj] = a[((size_t)(b * NS_ + i) * H_ + h) * N_ + j0 + jj];
    }
    __syncthreads();
    for (int jj = 0; jj < 64; ++jj) {
      float vv = vs[jj][dh];
#pragma unroll
      for (int ii = 0; ii < 6; ++ii) acc[ii] += as[ii * 4 + ib][jj] * vv;
    }
  }
#pragma unroll
  for (int ii = 0; ii < 6; ++ii) {
    int i = ii * 4 + ib;
    float dnm = asum[(b * NS_ + i) * H_ + h] + (float)N_ * EPS_;
    float val = (acc[ii] + EPS_ * vsum[(size_t)(b * H_ + h) * 64 + dh]) / dnm;
    upd[(size_t)(b * NS_ + i) * D_ + h * 64 + dh] = val;
  }
}

// ---------------- GRU elementwise ------------------------------------------
__global__ __launch_bounds__(256) void gru_kernel(const float* __restrict__ gi,
    const float* __restrict__ gh, const float* __restrict__ h, float* __restrict__ out)
{
  int e = blockIdx.x * 256 + threadIdx.x;
  int row = e >> 9, d = e & 511;
  const float* gir = gi + (size_t)row * 1536;
  const float* ghr = gh + (size_t)row * 1536;
  float ir = gir[d], iz = gir[512 + d], inn = gir[1024 + d];
  float hr = ghr[d], hz = ghr[512 + d], hn = ghr[1024 + d];
  float r = 1.f / (1.f + __expf(-(ir + hr)));
  float z = 1.f / (1.f + __expf(-(iz + hz)));
  float n = tanhf(inn + r * hn);
  out[e] = (1.f - z) * n + z * h[e];
}

// ---------------- LoRA: out[slot,:] += (x . A[idx]) . B[idx] ---------------
template<bool RELU_X>
__global__ __launch_bounds__(256) void lora_kernel(const float* __restrict__ x,
    const float* __restrict__ Am, const float* __restrict__ Bm,
    const int* __restrict__ idx, float* __restrict__ out, int Din, int Dout)
{
  int slot = blockIdx.x;
  int code = idx[slot];
  const float* xr = x + (size_t)slot * Din;
  const float* Ar = Am + (size_t)code * Din * R_;
  const float* Br = Bm + (size_t)code * R_ * Dout;
  float part[R_];
#pragma unroll
  for (int r = 0; r < R_; ++r) part[r] = 0.f;
  for (int d = threadIdx.x; d < Din; d += 256) {
    float xv = xr[d];
    if (RELU_X) xv = fmaxf(xv, 0.f);
#pragma unroll
    for (int r = 0; r < R_; ++r) part[r] += xv * Ar[(size_t)d * R_ + r];
  }
#pragma unroll
  for (int r = 0; r < R_; ++r)
#pragma unroll
    for (int o = 1; o < 64; o <<= 1) part[r] += __shfl_xor(part[r], o);
  __shared__ float tsh[4][R_];
  __shared__ float tfin[R_];
  int wave = threadIdx.x >> 6, lane = threadIdx.x & 63;
  if (lane == 0)
    for (int r = 0; r < R_; ++r) tsh[wave][r] = part[r];
  __syncthreads();
  if (threadIdx.x < R_)
    tfin[threadIdx.x] = (tsh[0][threadIdx.x] + tsh[1][threadIdx.x] +
                         tsh[2][threadIdx.x] + tsh[3][threadIdx.x]); // scale 8/8=1
  __syncthreads();
  for (int c = threadIdx.x; c < Dout; c += 256) {
    float acc = 0.f;
#pragma unroll
    for (int r = 0; r < R_; ++r) acc += tfin[r] * Br[(size_t)r * Dout + c];
    out[(size_t)slot * Dout + c] += acc;
  }
}

// ---------------- finalize: pack outputs -----------------------------------
__global__ __launch_bounds__(256) void finalize_kernel(const float* __restrict__ slots,
    const int* __restrict__ idx, const float* __restrict__ commit, float* __restrict__ out)
{
  int t = blockIdx.x * 256 + threadIdx.x;
  if (t < B_ * NS_ * D_) out[t] = slots[t];
  if (t < B_ * NS_) {
    float iv = (float)idx[t];
    out[1769472 + t] = iv;       // indices
    out[1769857 + t] = iv;       // indices (returned twice)
  }
  if (t == 0) out[1769856] = commit[0];
}

// ---------------------------------------------------------------------------
extern "C" void kernel_launch(void* const* d_in, const int* in_sizes, int n_in,
                              void* d_out, int out_size, void* d_ws, size_t ws_size,
                              hipStream_t stream)
{
  const float* inputs  = (const float*)d_in[0];
  const float* cond    = (const float*)d_in[1];
  const float* Wq      = (const float*)d_in[2];
  const float* Wk      = (const float*)d_in[3];
  const float* Wv      = (const float*)d_in[4];
  const float* w_ih    = (const float*)d_in[5];
  const float* w_hh    = (const float*)d_in[6];
  const float* b_ih    = (const float*)d_in[7];
  const float* b_hh    = (const float*)d_in[8];
  const float* ln_in_g = (const float*)d_in[9];
  const float* ln_in_b = (const float*)d_in[10];
  const float* ln_s_g  = (const float*)d_in[11];
  const float* ln_s_b  = (const float*)d_in[12];
  const float* ln_f_g  = (const float*)d_in[13];
  const float* ln_f_b  = (const float*)d_in[14];
  const float* W1      = (const float*)d_in[15];
  const float* b1      = (const float*)d_in[16];
  const float* W2      = (const float*)d_in[17];
  const float* b2      = (const float*)d_in[18];
  const float* A1      = (const float*)d_in[19];
  const float* B1m     = (const float*)d_in[20];
  const float* A2      = (const float*)d_in[21];
  const float* B2m     = (const float*)d_in[22];
  const float* codebook= (const float*)d_in[23];

  float* out = (float*)d_out;
  float* ws  = (float*)d_ws;

  size_t off = 0;
  float* xhat = ws + off;                 // reused as dots in the loop
  off += (size_t)B_ * N_ * D_;            // 33,554,432
  float* dots = xhat;                     // overlap: xhat dead after k/v
  float* kbuf = ws + off; off += (size_t)B_ * N_ * D_;
  float* vbuf = ws + off; off += (size_t)B_ * N_ * D_;
  float* slots_cur = ws + off; off += B_ * NS_ * D_;
  float* slots_gru = ws + off; off += B_ * NS_ * D_;
  float* sbuf      = ws + off; off += B_ * NS_ * D_;
  float* qb        = ws + off; off += B_ * NS_ * D_;
  float* updb      = ws + off; off += B_ * NS_ * D_;
  float* gib       = ws + off; off += B_ * NS_ * 3 * D_;
  float* ghb       = ws + off; off += B_ * NS_ * 3 * D_;
  float* h1b       = ws + off; off += B_ * NS_ * 4 * D_;
  float* vsumb     = ws + off; off += B_ * H_ * DH_;
  float* asumb     = ws + off; off += B_ * TT_;
  float* commitb   = ws + off; off += 1;
  int*   idxb      = (int*)(ws + off); off += B_ * NS_;

  // ---- phase A: LN(inputs), k, v, vsum ----
  ln_kernel<<<B_ * N_, 128, 0, stream>>>(inputs, ln_in_g, ln_in_b, xhat);
  gemm64<false, false, false><<<dim3(D_ / 64, (B_ * N_) / 64), 256, 0, stream>>>(
      xhat, Wk, nullptr, nullptr, kbuf, B_ * N_, D_, D_);
  gemm64<false, false, false><<<dim3(D_ / 64, (B_ * N_) / 64), 256, 0, stream>>>(
      xhat, Wv, nullptr, nullptr, vbuf, B_ * N_, D_, D_);
  vsum_kernel<<<B_ * H_, 256, 0, stream>>>(vbuf, vsumb);
  hipMemcpyAsync(slots_cur, cond, (size_t)B_ * NS_ * D_ * sizeof(float),
                 hipMemcpyDeviceToDevice, stream);

  // ---- phase B: 3 slot-attention iterations ----
  for (int it = 0; it < 3; ++it) {
    if (it > 0) {
      hipMemsetAsync(commitb, 0, sizeof(float), stream);
      vq_kernel<<<B_ * NS_, 256, 0, stream>>>(slots_cur, codebook, idxb, commitb);
    }
    ln_kernel<<<B_ * NS_, 128, 0, stream>>>(slots_cur, ln_s_g, ln_s_b, sbuf);
    gemm64<false, false, false><<<dim3(D_ / 64, (B_ * NS_) / 64), 256, 0, stream>>>(
        sbuf, Wq, nullptr, nullptr, qb, B_ * NS_, D_, D_);
    dots_kernel<<<dim3(N_ / 64, B_ * H_), 256, 0, stream>>>(qb, kbuf, dots);
    hipMemsetAsync(asumb, 0, (size_t)B_ * TT_ * sizeof(float), stream);
    softmax_kernel<<<dim3(N_ / 256, B_), 256, 0, stream>>>(
        dots, asumb, (it == 2) ? (out + (size_t)B_ * NS_ * D_) : nullptr);
    upd_kernel<<<B_ * H_, 256, 0, stream>>>(dots, vbuf, vsumb, asumb, updb);
    gemm64<true, false, false><<<dim3(1536 / 64, (B_ * NS_) / 64), 256, 0, stream>>>(
        updb, w_ih, b_ih, nullptr, gib, B_ * NS_, 3 * D_, D_);
    gemm64<true, false, false><<<dim3(1536 / 64, (B_ * NS_) / 64), 256, 0, stream>>>(
        slots_cur, w_hh, b_hh, nullptr, ghb, B_ * NS_, 3 * D_, D_);
    gru_kernel<<<(B_ * NS_ * D_) / 256, 256, 0, stream>>>(gib, ghb, slots_cur, slots_gru);
    ln_kernel<<<B_ * NS_, 128, 0, stream>>>(slots_gru, ln_f_g, ln_f_b, sbuf);
    gemm64<false, false, false><<<dim3(2048 / 64, (B_ * NS_) / 64), 256, 0, stream>>>(
        sbuf, W1, b1, nullptr, h1b, B_ * NS_, 4 * D_, D_);
    if (it > 0)
      lora_kernel<false><<<B_ * NS_, 256, 0, stream>>>(sbuf, A1, B1m, idxb, h1b, D_, 4 * D_);
    gemm64<false, true, true><<<dim3(D_ / 64, (B_ * NS_) / 64), 256, 0, stream>>>(
        h1b, W2, b2, slots_gru, slots_cur, B_ * NS_, D_, 4 * D_);
    if (it > 0)
      lora_kernel<true><<<B_ * NS_, 256, 0, stream>>>(h1b, A2, B2m, idxb, slots_cur, 4 * D_, D_);
  }

  finalize_kernel<<<(B_ * NS_ * D_) / 256, 256, 0, stream>>>(slots_cur, idxb, commitb, out);
}

// Round 3
// 4144.110 us; speedup vs baseline: 1.4965x; 1.4965x over previous
//
#include <hip/hip_runtime.h>
#include <hip/hip_bf16.h>
#include <math.h>

// ---------------------------------------------------------------------------
// SlotAttentionMod: B=16 N=4096 NS=24 D=512 H=8 DH=64 K=512 R=8 ITERS=3
// Round 3 (= round 2 resubmitted; bench never ran due to GPU timeout):
// k/v projections via split-bf16 (hi+lo) MFMA GEMM (error ~1e-5 rel,
// safe for the VQ argmin); upd occupancy fix (4-way j-split). Rest unchanged.
// ---------------------------------------------------------------------------

#define B_ 16
#define N_ 4096
#define NS_ 24
#define D_ 512
#define H_ 8
#define DH_ 64
#define KC_ 512
#define R_ 8
#define TT_ (NS_*H_)
#define EPS_ 1e-8f
#define BNSD_ (B_*NS_*D_)   // 196608

typedef unsigned short u16x8 __attribute__((ext_vector_type(8)));
typedef short s16x8 __attribute__((ext_vector_type(8)));
typedef float f32x4 __attribute__((ext_vector_type(4)));

__device__ inline unsigned short f2bf(float f) {
  unsigned int u = __float_as_uint(f);
  u += 0x7FFFu + ((u >> 16) & 1u);          // RNE
  return (unsigned short)(u >> 16);
}
__device__ inline float bf2f(unsigned short h) {
  return __uint_as_float(((unsigned int)h) << 16);
}

// ---------------- LayerNorm -> f32 out (slot path) -------------------------
__global__ __launch_bounds__(128) void ln_kernel(const float* __restrict__ X,
    const float* __restrict__ g, const float* __restrict__ bb,
    float* __restrict__ Y)
{
  int row = blockIdx.x;
  const float* xr = X + (size_t)row * D_;
  int t = threadIdx.x;
  float lv[4];
#pragma unroll
  for (int i = 0; i < 4; ++i) lv[i] = xr[t + 128 * i];
  float s = lv[0] + lv[1] + lv[2] + lv[3];
#pragma unroll
  for (int o = 1; o < 64; o <<= 1) s += __shfl_xor(s, o);
  __shared__ float sh[2], sh2[2];
  if ((t & 63) == 0) sh[t >> 6] = s;
  __syncthreads();
  float mean = (sh[0] + sh[1]) * (1.f / D_);
  float q = 0.f;
#pragma unroll
  for (int i = 0; i < 4; ++i) { float d = lv[i] - mean; q += d * d; }
#pragma unroll
  for (int o = 1; o < 64; o <<= 1) q += __shfl_xor(q, o);
  if ((t & 63) == 0) sh2[t >> 6] = q;
  __syncthreads();
  float var = (sh2[0] + sh2[1]) * (1.f / D_);
  float rstd = 1.0f / sqrtf(var + 1e-5f);
#pragma unroll
  for (int i = 0; i < 4; ++i) {
    int d = t + 128 * i;
    Y[(size_t)row * D_ + d] = (lv[i] - mean) * rstd * g[d] + bb[d];
  }
}

// ---------------- LayerNorm -> split-bf16 out [row][1024] (hi|lo) ----------
__global__ __launch_bounds__(128) void ln_hl_kernel(const float* __restrict__ X,
    const float* __restrict__ g, const float* __restrict__ bb,
    unsigned short* __restrict__ Y)
{
  int row = blockIdx.x;
  const float* xr = X + (size_t)row * D_;
  int t = threadIdx.x;
  float lv[4];
#pragma unroll
  for (int i = 0; i < 4; ++i) lv[i] = xr[t + 128 * i];
  float s = lv[0] + lv[1] + lv[2] + lv[3];
#pragma unroll
  for (int o = 1; o < 64; o <<= 1) s += __shfl_xor(s, o);
  __shared__ float sh[2], sh2[2];
  if ((t & 63) == 0) sh[t >> 6] = s;
  __syncthreads();
  float mean = (sh[0] + sh[1]) * (1.f / D_);
  float q = 0.f;
#pragma unroll
  for (int i = 0; i < 4; ++i) { float d = lv[i] - mean; q += d * d; }
#pragma unroll
  for (int o = 1; o < 64; o <<= 1) q += __shfl_xor(q, o);
  if ((t & 63) == 0) sh2[t >> 6] = q;
  __syncthreads();
  float var = (sh2[0] + sh2[1]) * (1.f / D_);
  float rstd = 1.0f / sqrtf(var + 1e-5f);
#pragma unroll
  for (int i = 0; i < 4; ++i) {
    int d = t + 128 * i;
    float y = (lv[i] - mean) * rstd * g[d] + bb[d];
    unsigned short h = f2bf(y);
    unsigned short l = f2bf(y - bf2f(h));
    Y[(size_t)row * 1024 + d] = h;
    Y[(size_t)row * 1024 + 512 + d] = l;
  }
}

// ---------------- weight transpose+split: W[512][512] -> WT[512][1536] -----
// WT[n][0:512]=hi(W[k][n]), [512:1024]=hi again, [1024:1536]=lo
__global__ __launch_bounds__(256) void wtrans_hl(const float* __restrict__ W,
                                                 unsigned short* __restrict__ WT)
{
  __shared__ float t[64][65];
  int n0 = blockIdx.x * 64, k0 = blockIdx.y * 64;
  for (int e = threadIdx.x; e < 4096; e += 256) {
    int kk = e >> 6, nn = e & 63;
    t[kk][nn] = W[(size_t)(k0 + kk) * 512 + n0 + nn];
  }
  __syncthreads();
  for (int e = threadIdx.x; e < 4096; e += 256) {
    int nn = e >> 6, kk = e & 63;
    float v = t[kk][nn];
    unsigned short h = f2bf(v);
    unsigned short l = f2bf(v - bf2f(h));
    size_t base = (size_t)(n0 + nn) * 1536 + (k0 + kk);
    WT[base] = h; WT[base + 512] = h; WT[base + 1024] = l;
  }
}

// ---------------- split-bf16 MFMA GEMM: C[M][512] = A_hl @ W_hl ------------
// A: [M][1024] bf16 (hi|lo), BT: [512][1536] bf16, K'=1536 over 24 steps of 64
// A-part of K': steps 0..15 read A cols [k*64, k*64+64) of the hi|lo 1024;
// B-part: BT cols [k*64,...) where [0:512]=hi (pairs with A-hi),
// [512:1024]=hi (pairs with A-lo), [1024:1536]=lo (pairs with A-hi again:
// steps 16..23 re-read A cols 0..512).
__global__ __launch_bounds__(256) void gemm_kv(
    const unsigned short* __restrict__ A, const unsigned short* __restrict__ BT,
    float* __restrict__ C)
{
  __shared__ unsigned short As[128 * 64];   // [row][64], XOR-swizzled 16B slots
  __shared__ unsigned short Bs[128 * 64];
  const int tid = threadIdx.x;
  const int lane = tid & 63, wid = tid >> 6;
  const int wm = wid >> 1, wn = wid & 1;
  const int g = lane >> 4, r16 = lane & 15;
  const int m0 = blockIdx.y * 128, n0 = blockIdx.x * 128;

  f32x4 acc[4][4] = {};
  u16x8 ra[4], rb[4];

  // per-thread staging slots: s = tid + 256*i, row = s>>3, q = s&7
  int srow[4], sj[4];
#pragma unroll
  for (int i = 0; i < 4; ++i) {
    int s = tid + (i << 8);
    srow[i] = s >> 3;
    sj[i] = (s & 7) ^ (srow[i] & 7);       // logical 16B-chunk (pre-swizzled src)
  }

  // prefetch step 0
#pragma unroll
  for (int i = 0; i < 4; ++i) {
    ra[i] = *(const u16x8*)(A + (size_t)(m0 + srow[i]) * 1024 + (sj[i] << 3));
    rb[i] = *(const u16x8*)(BT + (size_t)(n0 + srow[i]) * 1536 + (sj[i] << 3));
  }

  u16x8* Asw = (u16x8*)As;
  u16x8* Bsw = (u16x8*)Bs;
  const s16x8* Asv = (const s16x8*)As;
  const s16x8* Bsv = (const s16x8*)Bs;

  for (int kk = 0; kk < 24; ++kk) {
    __syncthreads();
#pragma unroll
    for (int i = 0; i < 4; ++i) {
      Asw[tid + (i << 8)] = ra[i];
      Bsw[tid + (i << 8)] = rb[i];
    }
    __syncthreads();
    if (kk + 1 < 24) {
      int k2 = kk + 1;
      int acol = ((k2 < 16) ? k2 : (k2 - 16)) * 64;
      int bcol = k2 * 64;
#pragma unroll
      for (int i = 0; i < 4; ++i) {
        ra[i] = *(const u16x8*)(A + (size_t)(m0 + srow[i]) * 1024 + acol + (sj[i] << 3));
        rb[i] = *(const u16x8*)(BT + (size_t)(n0 + srow[i]) * 1536 + bcol + (sj[i] << 3));
      }
    }
#pragma unroll
    for (int kh = 0; kh < 2; ++kh) {
      s16x8 af[4], bfr[4];
      int j = kh * 4 + g;
#pragma unroll
      for (int mi = 0; mi < 4; ++mi) {
        int m = wm * 64 + mi * 16 + r16;
        af[mi] = Asv[m * 8 + (j ^ (m & 7))];
      }
#pragma unroll
      for (int ni = 0; ni < 4; ++ni) {
        int n = wn * 64 + ni * 16 + r16;
        bfr[ni] = Bsv[n * 8 + (j ^ (n & 7))];
      }
#pragma unroll
      for (int mi = 0; mi < 4; ++mi)
#pragma unroll
        for (int ni = 0; ni < 4; ++ni)
          acc[mi][ni] = __builtin_amdgcn_mfma_f32_16x16x32_bf16(
              af[mi], bfr[ni], acc[mi][ni], 0, 0, 0);
    }
  }

  // C/D layout: col = lane&15, row = (lane>>4)*4 + reg
#pragma unroll
  for (int mi = 0; mi < 4; ++mi) {
    int mrow = m0 + wm * 64 + mi * 16 + g * 4;
#pragma unroll
    for (int ni = 0; ni < 4; ++ni) {
      int ncol = n0 + wn * 64 + ni * 16 + r16;
#pragma unroll
      for (int j = 0; j < 4; ++j)
        C[(size_t)(mrow + j) * 512 + ncol] = acc[mi][ni][j];
    }
  }
}

// ---------------- generic 64x64-tile f32 GEMM (small GEMMs) ----------------
template<bool BT, bool RELU_A, bool ADD_RES>
__global__ __launch_bounds__(256) void gemm64(
    const float* __restrict__ A, const float* __restrict__ B,
    const float* __restrict__ bias, const float* __restrict__ res,
    float* __restrict__ C, int M, int N, int K)
{
  __shared__ float As[16][64 + 1];
  __shared__ float Bs[16][64 + 1];
  int tx = threadIdx.x & 15, ty = threadIdx.x >> 4;
  int m0 = blockIdx.y * 64, n0 = blockIdx.x * 64;
  float acc[4][4] = {};
  for (int k0 = 0; k0 < K; k0 += 16) {
    for (int e = threadIdx.x; e < 64 * 16; e += 256) {
      int mm = e >> 4, kk = e & 15;
      float a = A[(size_t)(m0 + mm) * K + k0 + kk];
      if (RELU_A) a = fmaxf(a, 0.f);
      As[kk][mm] = a;
    }
    for (int e = threadIdx.x; e < 64 * 16; e += 256) {
      if (!BT) { int kk = e >> 6, nn = e & 63; Bs[kk][nn] = B[(size_t)(k0 + kk) * N + n0 + nn]; }
      else     { int nn = e >> 4, kk = e & 15; Bs[kk][nn] = B[(size_t)(n0 + nn) * K + k0 + kk]; }
    }
    __syncthreads();
#pragma unroll
    for (int kk = 0; kk < 16; ++kk) {
      float av[4], bv[4];
#pragma unroll
      for (int i = 0; i < 4; ++i) av[i] = As[kk][ty * 4 + i];
#pragma unroll
      for (int j = 0; j < 4; ++j) bv[j] = Bs[kk][tx * 4 + j];
#pragma unroll
      for (int i = 0; i < 4; ++i)
#pragma unroll
        for (int j = 0; j < 4; ++j) acc[i][j] += av[i] * bv[j];
    }
    __syncthreads();
  }
#pragma unroll
  for (int i = 0; i < 4; ++i) {
    int m = m0 + ty * 4 + i;
#pragma unroll
    for (int j = 0; j < 4; ++j) {
      int n = n0 + tx * 4 + j;
      float vv = acc[i][j];
      if (bias) vv += bias[n];
      if (ADD_RES) vv += res[(size_t)m * N + n];
      C[(size_t)m * N + n] = vv;
    }
  }
}

// ---------------- vsum[b,h,dh] = sum_j v[b,j,h,dh] -------------------------
__global__ __launch_bounds__(256) void vsum_kernel(const float* __restrict__ v,
                                                   float* __restrict__ vsum)
{
  int b = blockIdx.x >> 3, h = blockIdx.x & 7;
  int dh = threadIdx.x & 63, w = threadIdx.x >> 6;
  float acc = 0.f;
  for (int j = w * (N_ / 4); j < (w + 1) * (N_ / 4); ++j)
    acc += v[((size_t)b * N_ + j) * D_ + h * 64 + dh];
  __shared__ float sh[4][64];
  sh[w][dh] = acc;
  __syncthreads();
  if (w == 0)
    vsum[(size_t)blockIdx.x * 64 + dh] = sh[0][dh] + sh[1][dh] + sh[2][dh] + sh[3][dh];
}

// ---------------- VQ -------------------------------------------------------
__global__ __launch_bounds__(256) void vq_kernel(const float* __restrict__ slots,
    const float* __restrict__ cb, int* __restrict__ idx, float* __restrict__ commit)
{
  __shared__ float ss[D_];
  int slot = blockIdx.x;
  const float* sr = slots + (size_t)slot * D_;
  for (int d = threadIdx.x; d < D_; d += 256) ss[d] = sr[d];
  __syncthreads();
  float best = 1e30f; int bi = 0;
  for (int c = threadIdx.x; c < KC_; c += 256) {
    const float* cr = cb + (size_t)c * D_;
    float d2 = 0.f;
    for (int d = 0; d < D_; ++d) { float df = ss[d] - cr[d]; d2 += df * df; }
    if (d2 < best) { best = d2; bi = c; }
  }
  __shared__ float rb[256]; __shared__ int ri[256];
  rb[threadIdx.x] = best; ri[threadIdx.x] = bi;
  __syncthreads();
  for (int s = 128; s > 0; s >>= 1) {
    if (threadIdx.x < s) {
      float ob = rb[threadIdx.x + s]; int oi = ri[threadIdx.x + s];
      if (ob < rb[threadIdx.x] || (ob == rb[threadIdx.x] && oi < ri[threadIdx.x])) {
        rb[threadIdx.x] = ob; ri[threadIdx.x] = oi;
      }
    }
    __syncthreads();
  }
  if (threadIdx.x == 0) {
    idx[slot] = ri[0];
    atomicAdd(commit, rb[0] * (1.f / (B_ * NS_ * D_)));
  }
}

// ---------------- dots[b, i*8+h, j] ----------------------------------------
__global__ __launch_bounds__(256) void dots_kernel(const float* __restrict__ q,
    const float* __restrict__ k, float* __restrict__ dots)
{
  int b = blockIdx.y >> 3, h = blockIdx.y & 7;
  int j0 = blockIdx.x * 64;
  __shared__ float qs[NS_][DH_];
  __shared__ float ks[64][DH_ + 1];
  for (int e = threadIdx.x; e < NS_ * DH_; e += 256) {
    int i = e >> 6, dh = e & 63;
    qs[i][dh] = q[(size_t)(b * NS_ + i) * D_ + h * 64 + dh];
  }
  for (int e = threadIdx.x; e < 64 * 64; e += 256) {
    int jj = e >> 6, dh = e & 63;
    ks[jj][dh] = k[((size_t)b * N_ + j0 + jj) * D_ + h * 64 + dh];
  }
  __syncthreads();
  int jj = threadIdx.x & 63;
  int ib = threadIdx.x >> 6;
  float acc[6] = {0.f, 0.f, 0.f, 0.f, 0.f, 0.f};
  for (int dh = 0; dh < 64; ++dh) {
    float kv = ks[jj][dh];
#pragma unroll
    for (int ii = 0; ii < 6; ++ii) acc[ii] += qs[ii * 4 + ib][dh] * kv;
  }
#pragma unroll
  for (int ii = 0; ii < 6; ++ii) {
    int i = ii * 4 + ib;
    dots[((size_t)(b * NS_ + i) * H_ + h) * N_ + j0 + jj] = acc[ii] * 0.125f;
  }
}

// ---------------- softmax over 192 (slot,head) per (b,j) -------------------
__global__ __launch_bounds__(256) void softmax_kernel(float* __restrict__ dots,
    float* __restrict__ asum, float* __restrict__ attn)
{
  int b = blockIdx.y;
  int j = blockIdx.x * 256 + threadIdx.x;
  size_t base = (size_t)b * TT_ * N_ + j;
  float m = -1e30f;
  for (int t = 0; t < TT_; ++t) m = fmaxf(m, dots[base + (size_t)t * N_]);
  float S = 0.f;
  for (int t = 0; t < TT_; ++t) S += __expf(dots[base + (size_t)t * N_] - m);
  float rinv = 1.f / S;
  float am[NS_];
#pragma unroll
  for (int i = 0; i < NS_; ++i) am[i] = 0.f;
  for (int t = 0; t < TT_; ++t) {
    float w = __expf(dots[base + (size_t)t * N_] - m) * rinv;
    dots[base + (size_t)t * N_] = w;
    am[t >> 3] += w;
    float wsum = w;
#pragma unroll
    for (int o = 1; o < 64; o <<= 1) wsum += __shfl_xor(wsum, o);
    if ((threadIdx.x & 63) == 0) atomicAdd(&asum[b * TT_ + t], wsum);
  }
  if (attn) {
    for (int i = 0; i < NS_; ++i)
      attn[((size_t)b * NS_ + i) * N_ + j] = am[i] * (1.f / H_);
  }
}

// ---------------- upd partial: 4-way j-split -------------------------------
__global__ __launch_bounds__(256) void upd_part_kernel(const float* __restrict__ a,
    const float* __restrict__ v, float* __restrict__ part)
{
  int bh = blockIdx.x;
  int c = blockIdx.y;
  int b = bh >> 3, h = bh & 7;
  __shared__ float vs[64][DH_ + 1];
  __shared__ float as[NS_][64];
  int dh = threadIdx.x & 63;
  int ib = threadIdx.x >> 6;
  float acc[6] = {0.f, 0.f, 0.f, 0.f, 0.f, 0.f};
  for (int j0 = c * 1024; j0 < (c + 1) * 1024; j0 += 64) {
    __syncthreads();
    for (int e = threadIdx.x; e < 64 * 64; e += 256) {
      int jj = e >> 6, d2 = e & 63;
      vs[jj][d2] = v[((size_t)b * N_ + j0 + jj) * D_ + h * 64 + d2];
    }
    for (int e = threadIdx.x; e < NS_ * 64; e += 256) {
      int i = e >> 6, jj = e & 63;
      as[i][jj] = a[((size_t)(b * NS_ + i) * H_ + h) * N_ + j0 + jj];
    }
    __syncthreads();
    for (int jj = 0; jj < 64; ++jj) {
      float vv = vs[jj][dh];
#pragma unroll
      for (int ii = 0; ii < 6; ++ii) acc[ii] += as[ii * 4 + ib][jj] * vv;
    }
  }
#pragma unroll
  for (int ii = 0; ii < 6; ++ii) {
    int i = ii * 4 + ib;
    part[((size_t)c * B_ * NS_ + b * NS_ + i) * D_ + h * 64 + dh] = acc[ii];
  }
}

__global__ __launch_bounds__(256) void upd_fin_kernel(const float* __restrict__ part,
    const float* __restrict__ vsum, const float* __restrict__ asum,
    float* __restrict__ upd)
{
  int e = blockIdx.x * 256 + threadIdx.x;  // over B*NS*D
  int d = e & 511, bi = e >> 9;
  int b = bi / NS_, h = d >> 6, dh = d & 63;
  float s = part[e] + part[BNSD_ + e] + part[2 * BNSD_ + e] + part[3 * BNSD_ + e];
  float dnm = asum[bi * H_ + h] + (float)N_ * EPS_;
  upd[e] = (s + EPS_ * vsum[(b * H_ + h) * 64 + dh]) / dnm;
}

// ---------------- GRU elementwise ------------------------------------------
__global__ __launch_bounds__(256) void gru_kernel(const float* __restrict__ gi,
    const float* __restrict__ gh, const float* __restrict__ h, float* __restrict__ out)
{
  int e = blockIdx.x * 256 + threadIdx.x;
  int row = e >> 9, d = e & 511;
  const float* gir = gi + (size_t)row * 1536;
  const float* ghr = gh + (size_t)row * 1536;
  float ir = gir[d], iz = gir[512 + d], inn = gir[1024 + d];
  float hr = ghr[d], hz = ghr[512 + d], hn = ghr[1024 + d];
  float r = 1.f / (1.f + __expf(-(ir + hr)));
  float z = 1.f / (1.f + __expf(-(iz + hz)));
  float n = tanhf(inn + r * hn);
  out[e] = (1.f - z) * n + z * h[e];
}

// ---------------- LoRA -----------------------------------------------------
template<bool RELU_X>
__global__ __launch_bounds__(256) void lora_kernel(const float* __restrict__ x,
    const float* __restrict__ Am, const float* __restrict__ Bm,
    const int* __restrict__ idx, float* __restrict__ out, int Din, int Dout)
{
  int slot = blockIdx.x;
  int code = idx[slot];
  const float* xr = x + (size_t)slot * Din;
  const float* Ar = Am + (size_t)code * Din * R_;
  const float* Br = Bm + (size_t)code * R_ * Dout;
  float part[R_];
#pragma unroll
  for (int r = 0; r < R_; ++r) part[r] = 0.f;
  for (int d = threadIdx.x; d < Din; d += 256) {
    float xv = xr[d];
    if (RELU_X) xv = fmaxf(xv, 0.f);
#pragma unroll
    for (int r = 0; r < R_; ++r) part[r] += xv * Ar[(size_t)d * R_ + r];
  }
#pragma unroll
  for (int r = 0; r < R_; ++r)
#pragma unroll
    for (int o = 1; o < 64; o <<= 1) part[r] += __shfl_xor(part[r], o);
  __shared__ float tsh[4][R_];
  __shared__ float tfin[R_];
  int wave = threadIdx.x >> 6, lane = threadIdx.x & 63;
  if (lane == 0)
    for (int r = 0; r < R_; ++r) tsh[wave][r] = part[r];
  __syncthreads();
  if (threadIdx.x < R_)
    tfin[threadIdx.x] = (tsh[0][threadIdx.x] + tsh[1][threadIdx.x] +
                         tsh[2][threadIdx.x] + tsh[3][threadIdx.x]);
  __syncthreads();
  for (int c = threadIdx.x; c < Dout; c += 256) {
    float acc = 0.f;
#pragma unroll
    for (int r = 0; r < R_; ++r) acc += tfin[r] * Br[(size_t)r * Dout + c];
    out[(size_t)slot * Dout + c] += acc;
  }
}

// ---------------- finalize -------------------------------------------------
__global__ __launch_bounds__(256) void finalize_kernel(const float* __restrict__ slots,
    const int* __restrict__ idx, const float* __restrict__ commit, float* __restrict__ out)
{
  int t = blockIdx.x * 256 + threadIdx.x;
  if (t < B_ * NS_ * D_) out[t] = slots[t];
  if (t < B_ * NS_) {
    float iv = (float)idx[t];
    out[1769472 + t] = iv;
    out[1769857 + t] = iv;
  }
  if (t == 0) out[1769856] = commit[0];
}

// ---------------------------------------------------------------------------
extern "C" void kernel_launch(void* const* d_in, const int* in_sizes, int n_in,
                              void* d_out, int out_size, void* d_ws, size_t ws_size,
                              hipStream_t stream)
{
  const float* inputs  = (const float*)d_in[0];
  const float* cond    = (const float*)d_in[1];
  const float* Wq      = (const float*)d_in[2];
  const float* Wk      = (const float*)d_in[3];
  const float* Wv      = (const float*)d_in[4];
  const float* w_ih    = (const float*)d_in[5];
  const float* w_hh    = (const float*)d_in[6];
  const float* b_ih    = (const float*)d_in[7];
  const float* b_hh    = (const float*)d_in[8];
  const float* ln_in_g = (const float*)d_in[9];
  const float* ln_in_b = (const float*)d_in[10];
  const float* ln_s_g  = (const float*)d_in[11];
  const float* ln_s_b  = (const float*)d_in[12];
  const float* ln_f_g  = (const float*)d_in[13];
  const float* ln_f_b  = (const float*)d_in[14];
  const float* W1      = (const float*)d_in[15];
  const float* b1      = (const float*)d_in[16];
  const float* W2      = (const float*)d_in[17];
  const float* b2      = (const float*)d_in[18];
  const float* A1      = (const float*)d_in[19];
  const float* B1m     = (const float*)d_in[20];
  const float* A2      = (const float*)d_in[21];
  const float* B2m     = (const float*)d_in[22];
  const float* codebook= (const float*)d_in[23];

  float* out = (float*)d_out;
  float* ws  = (float*)d_ws;

  size_t off = 0;
  // split-bf16 xhat: [65536][1024] ushorts = 33.5M float-slots.
  // After k/v are computed this region is reused for dots (12.6M) + part (0.79M).
  unsigned short* xhat_hl = (unsigned short*)(ws + off);
  float* dots = ws + off;
  float* part = ws + off + 12582912;
  off += 33554432;
  float* kbuf = ws + off; off += 33554432;
  float* vbuf = ws + off; off += 33554432;
  unsigned short* WkT = (unsigned short*)(ws + off); off += 393216;  // 512*1536 bf16
  unsigned short* WvT = (unsigned short*)(ws + off); off += 393216;
  float* slots_cur = ws + off; off += BNSD_;
  float* slots_gru = ws + off; off += BNSD_;
  float* sbuf      = ws + off; off += BNSD_;
  float* qb        = ws + off; off += BNSD_;
  float* updb      = ws + off; off += BNSD_;
  float* gib       = ws + off; off += B_ * NS_ * 3 * D_;
  float* ghb       = ws + off; off += B_ * NS_ * 3 * D_;
  float* h1b       = ws + off; off += B_ * NS_ * 4 * D_;
  float* vsumb     = ws + off; off += B_ * H_ * DH_;
  float* asumb     = ws + off; off += B_ * TT_;
  float* commitb   = ws + off; off += 1;
  int*   idxb      = (int*)(ws + off); off += B_ * NS_;

  // ---- phase A: LN(inputs)->hi/lo bf16, weight prep, k/v via MFMA ----
  ln_hl_kernel<<<B_ * N_, 128, 0, stream>>>(inputs, ln_in_g, ln_in_b, xhat_hl);
  wtrans_hl<<<dim3(8, 8), 256, 0, stream>>>(Wk, WkT);
  wtrans_hl<<<dim3(8, 8), 256, 0, stream>>>(Wv, WvT);
  gemm_kv<<<dim3(4, 512), 256, 0, stream>>>(xhat_hl, WkT, kbuf);
  gemm_kv<<<dim3(4, 512), 256, 0, stream>>>(xhat_hl, WvT, vbuf);
  vsum_kernel<<<B_ * H_, 256, 0, stream>>>(vbuf, vsumb);
  hipMemcpyAsync(slots_cur, cond, (size_t)BNSD_ * sizeof(float),
                 hipMemcpyDeviceToDevice, stream);

  // ---- phase B: 3 slot-attention iterations ----
  for (int it = 0; it < 3; ++it) {
    if (it > 0) {
      hipMemsetAsync(commitb, 0, sizeof(float), stream);
      vq_kernel<<<B_ * NS_, 256, 0, stream>>>(slots_cur, codebook, idxb, commitb);
    }
    ln_kernel<<<B_ * NS_, 128, 0, stream>>>(slots_cur, ln_s_g, ln_s_b, sbuf);
    gemm64<false, false, false><<<dim3(D_ / 64, (B_ * NS_) / 64), 256, 0, stream>>>(
        sbuf, Wq, nullptr, nullptr, qb, B_ * NS_, D_, D_);
    dots_kernel<<<dim3(N_ / 64, B_ * H_), 256, 0, stream>>>(qb, kbuf, dots);
    hipMemsetAsync(asumb, 0, (size_t)B_ * TT_ * sizeof(float), stream);
    softmax_kernel<<<dim3(N_ / 256, B_), 256, 0, stream>>>(
        dots, asumb, (it == 2) ? (out + (size_t)BNSD_) : nullptr);
    upd_part_kernel<<<dim3(B_ * H_, 4), 256, 0, stream>>>(dots, vbuf, part);
    upd_fin_kernel<<<BNSD_ / 256, 256, 0, stream>>>(part, vsumb, asumb, updb);
    gemm64<true, false, false><<<dim3(1536 / 64, (B_ * NS_) / 64), 256, 0, stream>>>(
        updb, w_ih, b_ih, nullptr, gib, B_ * NS_, 3 * D_, D_);
    gemm64<true, false, false><<<dim3(1536 / 64, (B_ * NS_) / 64), 256, 0, stream>>>(
        slots_cur, w_hh, b_hh, nullptr, ghb, B_ * NS_, 3 * D_, D_);
    gru_kernel<<<BNSD_ / 256, 256, 0, stream>>>(gib, ghb, slots_cur, slots_gru);
    ln_kernel<<<B_ * NS_, 128, 0, stream>>>(slots_gru, ln_f_g, ln_f_b, sbuf);
    gemm64<false, false, false><<<dim3(2048 / 64, (B_ * NS_) / 64), 256, 0, stream>>>(
        sbuf, W1, b1, nullptr, h1b, B_ * NS_, 4 * D_, D_);
    if (it > 0)
      lora_kernel<false><<<B_ * NS_, 256, 0, stream>>>(sbuf, A1, B1m, idxb, h1b, D_, 4 * D_);
    gemm64<false, true, true><<<dim3(D_ / 64, (B_ * NS_) / 64), 256, 0, stream>>>(
        h1b, W2, b2, slots_gru, slots_cur, B_ * NS_, D_, 4 * D_);
    if (it > 0)
      lora_kernel<true><<<B_ * NS_, 256, 0, stream>>>(h1b, A2, B2m, idxb, slots_cur, 4 * D_, D_);
  }

  finalize_kernel<<<BNSD_ / 256, 256, 0, stream>>>(slots_cur, idxb, commitb, out);
}

// Round 4
// 2002.811 us; speedup vs baseline: 3.0964x; 2.0691x over previous
//
#include <hip/hip_runtime.h>
#include <hip/hip_bf16.h>
#include <math.h>

// ---------------------------------------------------------------------------
// SlotAttentionMod: B=16 N=4096 NS=24 D=512 H=8 DH=64 K=512 R=8 ITERS=3
// Round 4: all per-iter small GEMMs (q, gi, gh, W1, W2) -> split-bf16 MFMA
// with split-K partials (gemm_sp) + fused reduce/epilogue (redep).
// Producers dual-write f32 + (hi|lo) bf16 operands. k/v via gemm_kv (r3).
// ---------------------------------------------------------------------------

#define B_ 16
#define N_ 4096
#define NS_ 24
#define D_ 512
#define H_ 8
#define DH_ 64
#define KC_ 512
#define R_ 8
#define TT_ (NS_*H_)
#define EPS_ 1e-8f
#define BNSD_ (B_*NS_*D_)   // 196608
#define M_ 384              // B*NS

typedef unsigned short u16x8 __attribute__((ext_vector_type(8)));
typedef short s16x8 __attribute__((ext_vector_type(8)));
typedef float f32x4 __attribute__((ext_vector_type(4)));

__device__ inline unsigned short f2bf(float f) {
  unsigned int u = __float_as_uint(f);
  u += 0x7FFFu + ((u >> 16) & 1u);          // RNE
  return (unsigned short)(u >> 16);
}
__device__ inline float bf2f(unsigned short h) {
  return __uint_as_float(((unsigned int)h) << 16);
}

// ---------------- LayerNorm -> split-bf16 out [row][1024] (hi|lo) ----------
__global__ __launch_bounds__(128) void ln_hl_kernel(const float* __restrict__ X,
    const float* __restrict__ g, const float* __restrict__ bb,
    unsigned short* __restrict__ Y)
{
  int row = blockIdx.x;
  const float* xr = X + (size_t)row * D_;
  int t = threadIdx.x;
  float lv[4];
#pragma unroll
  for (int i = 0; i < 4; ++i) lv[i] = xr[t + 128 * i];
  float s = lv[0] + lv[1] + lv[2] + lv[3];
#pragma unroll
  for (int o = 1; o < 64; o <<= 1) s += __shfl_xor(s, o);
  __shared__ float sh[2], sh2[2];
  if ((t & 63) == 0) sh[t >> 6] = s;
  __syncthreads();
  float mean = (sh[0] + sh[1]) * (1.f / D_);
  float q = 0.f;
#pragma unroll
  for (int i = 0; i < 4; ++i) { float d = lv[i] - mean; q += d * d; }
#pragma unroll
  for (int o = 1; o < 64; o <<= 1) q += __shfl_xor(q, o);
  if ((t & 63) == 0) sh2[t >> 6] = q;
  __syncthreads();
  float var = (sh2[0] + sh2[1]) * (1.f / D_);
  float rstd = 1.0f / sqrtf(var + 1e-5f);
#pragma unroll
  for (int i = 0; i < 4; ++i) {
    int d = t + 128 * i;
    float y = (lv[i] - mean) * rstd * g[d] + bb[d];
    unsigned short h = f2bf(y);
    unsigned short l = f2bf(y - bf2f(h));
    Y[(size_t)row * 1024 + d] = h;
    Y[(size_t)row * 1024 + 512 + d] = l;
  }
}

// ---------------- LayerNorm -> f32 AND hl outputs --------------------------
__global__ __launch_bounds__(128) void ln_dual_kernel(const float* __restrict__ X,
    const float* __restrict__ g, const float* __restrict__ bb,
    float* __restrict__ Yf, unsigned short* __restrict__ Yhl)
{
  int row = blockIdx.x;
  const float* xr = X + (size_t)row * D_;
  int t = threadIdx.x;
  float lv[4];
#pragma unroll
  for (int i = 0; i < 4; ++i) lv[i] = xr[t + 128 * i];
  float s = lv[0] + lv[1] + lv[2] + lv[3];
#pragma unroll
  for (int o = 1; o < 64; o <<= 1) s += __shfl_xor(s, o);
  __shared__ float sh[2], sh2[2];
  if ((t & 63) == 0) sh[t >> 6] = s;
  __syncthreads();
  float mean = (sh[0] + sh[1]) * (1.f / D_);
  float q = 0.f;
#pragma unroll
  for (int i = 0; i < 4; ++i) { float d = lv[i] - mean; q += d * d; }
#pragma unroll
  for (int o = 1; o < 64; o <<= 1) q += __shfl_xor(q, o);
  if ((t & 63) == 0) sh2[t >> 6] = q;
  __syncthreads();
  float var = (sh2[0] + sh2[1]) * (1.f / D_);
  float rstd = 1.0f / sqrtf(var + 1e-5f);
#pragma unroll
  for (int i = 0; i < 4; ++i) {
    int d = t + 128 * i;
    float y = (lv[i] - mean) * rstd * g[d] + bb[d];
    Yf[(size_t)row * D_ + d] = y;
    unsigned short h = f2bf(y);
    unsigned short l = f2bf(y - bf2f(h));
    Yhl[(size_t)row * 1024 + d] = h;
    Yhl[(size_t)row * 1024 + 512 + d] = l;
  }
}

// ---------------- generalized weight transpose+split -----------------------
// W [K][N] f32 -> WT [N][3K] u16: [0:K]=hi, [K:2K]=hi, [2K:3K]=lo
__global__ __launch_bounds__(256) void wtrans_g(const float* __restrict__ W,
    unsigned short* __restrict__ WT, int K, int N)
{
  __shared__ float t[64][65];
  int n0 = blockIdx.x * 64, k0 = blockIdx.y * 64;
  for (int e = threadIdx.x; e < 4096; e += 256) {
    int kk = e >> 6, nn = e & 63;
    t[kk][nn] = W[(size_t)(k0 + kk) * N + n0 + nn];
  }
  __syncthreads();
  for (int e = threadIdx.x; e < 4096; e += 256) {
    int nn = e >> 6, kk = e & 63;
    float v = t[kk][nn];
    unsigned short h = f2bf(v);
    unsigned short l = f2bf(v - bf2f(h));
    size_t base = (size_t)(n0 + nn) * 3 * K + (k0 + kk);
    WT[base] = h; WT[base + K] = h; WT[base + 2 * K] = l;
  }
}

// ---------------- split (no transpose): W [N][K] -> WT [N][3K] -------------
__global__ __launch_bounds__(256) void wsplit_nm(const float* __restrict__ W,
    unsigned short* __restrict__ WT, int K, int total)
{
  int e = blockIdx.x * 256 + threadIdx.x;
  if (e >= total) return;
  int n = e / K, k = e % K;
  float v = W[e];
  unsigned short h = f2bf(v);
  unsigned short l = f2bf(v - bf2f(h));
  size_t base = (size_t)n * 3 * K + k;
  WT[base] = h; WT[base + K] = h; WT[base + 2 * K] = l;
}

// ---------------- f32 -> hl (optional f32 copy) ----------------------------
__global__ __launch_bounds__(256) void f32tohl_kernel(const float* __restrict__ X,
    float* __restrict__ Cout, unsigned short* __restrict__ HL, int total)
{
  int e = blockIdx.x * 256 + threadIdx.x;
  if (e >= total) return;
  float v = X[e];
  if (Cout) Cout[e] = v;
  int m = e >> 9, d = e & 511;
  unsigned short h = f2bf(v);
  unsigned short l = f2bf(v - bf2f(h));
  HL[(size_t)m * 1024 + d] = h;
  HL[(size_t)m * 1024 + 512 + d] = l;
}

// ---------------- relu(h1) -> hl [m][4096] ---------------------------------
__global__ __launch_bounds__(256) void reluhl_kernel(const float* __restrict__ X,
    unsigned short* __restrict__ HL)
{
  int e = blockIdx.x * 256 + threadIdx.x;   // < 384*2048
  float v = fmaxf(X[e], 0.f);
  int m = e >> 11, d = e & 2047;
  unsigned short h = f2bf(v);
  unsigned short l = f2bf(v - bf2f(h));
  HL[(size_t)m * 4096 + d] = h;
  HL[(size_t)m * 4096 + 2048 + d] = l;
}

// ---------------- split-bf16 MFMA GEMM: k/v (128x128 tile) -----------------
__global__ __launch_bounds__(256) void gemm_kv(
    const unsigned short* __restrict__ A, const unsigned short* __restrict__ BT,
    float* __restrict__ C)
{
  __shared__ unsigned short As[128 * 64];
  __shared__ unsigned short Bs[128 * 64];
  const int tid = threadIdx.x;
  const int lane = tid & 63, wid = tid >> 6;
  const int wm = wid >> 1, wn = wid & 1;
  const int g = lane >> 4, r16 = lane & 15;
  const int m0 = blockIdx.y * 128, n0 = blockIdx.x * 128;

  f32x4 acc[4][4] = {};
  u16x8 ra[4], rb[4];
  int srow[4], sj[4];
#pragma unroll
  for (int i = 0; i < 4; ++i) {
    int s = tid + (i << 8);
    srow[i] = s >> 3;
    sj[i] = (s & 7) ^ (srow[i] & 7);
  }
#pragma unroll
  for (int i = 0; i < 4; ++i) {
    ra[i] = *(const u16x8*)(A + (size_t)(m0 + srow[i]) * 1024 + (sj[i] << 3));
    rb[i] = *(const u16x8*)(BT + (size_t)(n0 + srow[i]) * 1536 + (sj[i] << 3));
  }
  u16x8* Asw = (u16x8*)As;
  u16x8* Bsw = (u16x8*)Bs;
  const s16x8* Asv = (const s16x8*)As;
  const s16x8* Bsv = (const s16x8*)Bs;

  for (int kk = 0; kk < 24; ++kk) {
    __syncthreads();
#pragma unroll
    for (int i = 0; i < 4; ++i) {
      Asw[tid + (i << 8)] = ra[i];
      Bsw[tid + (i << 8)] = rb[i];
    }
    __syncthreads();
    if (kk + 1 < 24) {
      int k2 = kk + 1;
      int acol = ((k2 < 16) ? k2 : (k2 - 16)) * 64;
      int bcol = k2 * 64;
#pragma unroll
      for (int i = 0; i < 4; ++i) {
        ra[i] = *(const u16x8*)(A + (size_t)(m0 + srow[i]) * 1024 + acol + (sj[i] << 3));
        rb[i] = *(const u16x8*)(BT + (size_t)(n0 + srow[i]) * 1536 + bcol + (sj[i] << 3));
      }
    }
#pragma unroll
    for (int kh = 0; kh < 2; ++kh) {
      s16x8 af[4], bfr[4];
      int j = kh * 4 + g;
#pragma unroll
      for (int mi = 0; mi < 4; ++mi) {
        int m = wm * 64 + mi * 16 + r16;
        af[mi] = Asv[m * 8 + (j ^ (m & 7))];
      }
#pragma unroll
      for (int ni = 0; ni < 4; ++ni) {
        int n = wn * 64 + ni * 16 + r16;
        bfr[ni] = Bsv[n * 8 + (j ^ (n & 7))];
      }
#pragma unroll
      for (int mi = 0; mi < 4; ++mi)
#pragma unroll
        for (int ni = 0; ni < 4; ++ni)
          acc[mi][ni] = __builtin_amdgcn_mfma_f32_16x16x32_bf16(
              af[mi], bfr[ni], acc[mi][ni], 0, 0, 0);
    }
  }
#pragma unroll
  for (int mi = 0; mi < 4; ++mi) {
    int mrow = m0 + wm * 64 + mi * 16 + g * 4;
#pragma unroll
    for (int ni = 0; ni < 4; ++ni) {
      int ncol = n0 + wn * 64 + ni * 16 + r16;
#pragma unroll
      for (int j = 0; j < 4; ++j)
        C[(size_t)(mrow + j) * 512 + ncol] = acc[mi][ni][j];
    }
  }
}

// ---------------- split-bf16 MFMA small GEMM with split-K ------------------
// A [M][2K] hl, WT [N][3K], part [Z][384][N]. 128x64 tile, steps of 64 K'.
__global__ __launch_bounds__(256) void gemm_sp(
    const unsigned short* __restrict__ A, const unsigned short* __restrict__ WT,
    float* __restrict__ part, int N, int K, int S)
{
  __shared__ unsigned short As[128 * 64];
  __shared__ unsigned short Bs[64 * 64];
  const int tid = threadIdx.x;
  const int lane = tid & 63, wid = tid >> 6;
  const int wm = wid >> 1, wn = wid & 1;
  const int g = lane >> 4, r16 = lane & 15;
  const int n0 = blockIdx.x * 64, m0 = blockIdx.y * 128, z = blockIdx.z;
  const int twoK = 2 * K;
  const size_t ldb = (size_t)3 * K;

  f32x4 acc[4][2] = {};
  u16x8 ra[4], rb[2];
  int arow[4], aj[4], brow[2], bj[2];
#pragma unroll
  for (int i = 0; i < 4; ++i) {
    int s = tid + (i << 8);
    arow[i] = s >> 3; aj[i] = (s & 7) ^ (arow[i] & 7);
  }
#pragma unroll
  for (int i = 0; i < 2; ++i) {
    int s = tid + (i << 8);
    brow[i] = s >> 3; bj[i] = (s & 7) ^ (brow[i] & 7);
  }
  const int s0 = z * S;
  {
    int c = s0 * 64;
    int ac = (c < twoK) ? c : c - twoK;
#pragma unroll
    for (int i = 0; i < 4; ++i)
      ra[i] = *(const u16x8*)(A + (size_t)(m0 + arow[i]) * twoK + ac + (aj[i] << 3));
#pragma unroll
    for (int i = 0; i < 2; ++i)
      rb[i] = *(const u16x8*)(WT + (size_t)(n0 + brow[i]) * ldb + c + (bj[i] << 3));
  }
  u16x8* Asw = (u16x8*)As;
  u16x8* Bsw = (u16x8*)Bs;
  const s16x8* Asv = (const s16x8*)As;
  const s16x8* Bsv = (const s16x8*)Bs;

  for (int st = 0; st < S; ++st) {
    __syncthreads();
#pragma unroll
    for (int i = 0; i < 4; ++i) Asw[tid + (i << 8)] = ra[i];
#pragma unroll
    for (int i = 0; i < 2; ++i) Bsw[tid + (i << 8)] = rb[i];
    __syncthreads();
    if (st + 1 < S) {
      int c = (s0 + st + 1) * 64;
      int ac = (c < twoK) ? c : c - twoK;
#pragma unroll
      for (int i = 0; i < 4; ++i)
        ra[i] = *(const u16x8*)(A + (size_t)(m0 + arow[i]) * twoK + ac + (aj[i] << 3));
#pragma unroll
      for (int i = 0; i < 2; ++i)
        rb[i] = *(const u16x8*)(WT + (size_t)(n0 + brow[i]) * ldb + c + (bj[i] << 3));
    }
#pragma unroll
    for (int kh = 0; kh < 2; ++kh) {
      int j = kh * 4 + g;
      s16x8 af[4], bf2v[2];
#pragma unroll
      for (int mi = 0; mi < 4; ++mi) {
        int m = wm * 64 + mi * 16 + r16;
        af[mi] = Asv[m * 8 + (j ^ (m & 7))];
      }
#pragma unroll
      for (int ni = 0; ni < 2; ++ni) {
        int n = wn * 32 + ni * 16 + r16;
        bf2v[ni] = Bsv[n * 8 + (j ^ (n & 7))];
      }
#pragma unroll
      for (int mi = 0; mi < 4; ++mi)
#pragma unroll
        for (int ni = 0; ni < 2; ++ni)
          acc[mi][ni] = __builtin_amdgcn_mfma_f32_16x16x32_bf16(
              af[mi], bf2v[ni], acc[mi][ni], 0, 0, 0);
    }
  }
  size_t zb = (size_t)z * M_ * N;
#pragma unroll
  for (int mi = 0; mi < 4; ++mi) {
    int mr = m0 + wm * 64 + mi * 16 + g * 4;
#pragma unroll
    for (int ni = 0; ni < 2; ++ni) {
      int nc = n0 + wn * 32 + ni * 16 + r16;
#pragma unroll
      for (int j2 = 0; j2 < 4; ++j2)
        part[zb + (size_t)(mr + j2) * N + nc] = acc[mi][ni][j2];
    }
  }
}

// ---------------- reduce partials + epilogue -------------------------------
template<bool BIAS, bool RES, bool WHL>
__global__ __launch_bounds__(256) void redep(const float* __restrict__ part,
    const float* __restrict__ bias, const float* __restrict__ res,
    float* __restrict__ C, unsigned short* __restrict__ HL, int N, int Z)
{
  int e = blockIdx.x * 256 + threadIdx.x;   // < 384*N
  size_t MN = (size_t)M_ * N;
  float v = 0.f;
  for (int z = 0; z < Z; ++z) v += part[(size_t)z * MN + e];
  int m = e / N, n = e - m * N;
  if (BIAS) v += bias[n];
  if (RES) v += res[e];
  C[e] = v;
  if (WHL) {
    unsigned short h = f2bf(v), l = f2bf(v - bf2f(h));
    HL[(size_t)m * 2 * N + n] = h;
    HL[(size_t)m * 2 * N + N + n] = l;
  }
}

// ---------------- vsum[b,h,dh] = sum_j v[b,j,h,dh] -------------------------
__global__ __launch_bounds__(256) void vsum_kernel(const float* __restrict__ v,
                                                   float* __restrict__ vsum)
{
  int b = blockIdx.x >> 3, h = blockIdx.x & 7;
  int dh = threadIdx.x & 63, w = threadIdx.x >> 6;
  float acc = 0.f;
  for (int j = w * (N_ / 4); j < (w + 1) * (N_ / 4); ++j)
    acc += v[((size_t)b * N_ + j) * D_ + h * 64 + dh];
  __shared__ float sh[4][64];
  sh[w][dh] = acc;
  __syncthreads();
  if (w == 0)
    vsum[(size_t)blockIdx.x * 64 + dh] = sh[0][dh] + sh[1][dh] + sh[2][dh] + sh[3][dh];
}

// ---------------- VQ -------------------------------------------------------
__global__ __launch_bounds__(256) void vq_kernel(const float* __restrict__ slots,
    const float* __restrict__ cb, int* __restrict__ idx, float* __restrict__ commit)
{
  __shared__ float ss[D_];
  int slot = blockIdx.x;
  const float* sr = slots + (size_t)slot * D_;
  for (int d = threadIdx.x; d < D_; d += 256) ss[d] = sr[d];
  __syncthreads();
  float best = 1e30f; int bi = 0;
  for (int c = threadIdx.x; c < KC_; c += 256) {
    const float* cr = cb + (size_t)c * D_;
    float d2 = 0.f;
    for (int d = 0; d < D_; ++d) { float df = ss[d] - cr[d]; d2 += df * df; }
    if (d2 < best) { best = d2; bi = c; }
  }
  __shared__ float rb[256]; __shared__ int ri[256];
  rb[threadIdx.x] = best; ri[threadIdx.x] = bi;
  __syncthreads();
  for (int s = 128; s > 0; s >>= 1) {
    if (threadIdx.x < s) {
      float ob = rb[threadIdx.x + s]; int oi = ri[threadIdx.x + s];
      if (ob < rb[threadIdx.x] || (ob == rb[threadIdx.x] && oi < ri[threadIdx.x])) {
        rb[threadIdx.x] = ob; ri[threadIdx.x] = oi;
      }
    }
    __syncthreads();
  }
  if (threadIdx.x == 0) {
    idx[slot] = ri[0];
    atomicAdd(commit, rb[0] * (1.f / (B_ * NS_ * D_)));
  }
}

// ---------------- dots[b, i*8+h, j] ----------------------------------------
__global__ __launch_bounds__(256) void dots_kernel(const float* __restrict__ q,
    const float* __restrict__ k, float* __restrict__ dots)
{
  int b = blockIdx.y >> 3, h = blockIdx.y & 7;
  int j0 = blockIdx.x * 64;
  __shared__ float qs[NS_][DH_];
  __shared__ float ks[64][DH_ + 1];
  for (int e = threadIdx.x; e < NS_ * DH_; e += 256) {
    int i = e >> 6, dh = e & 63;
    qs[i][dh] = q[(size_t)(b * NS_ + i) * D_ + h * 64 + dh];
  }
  for (int e = threadIdx.x; e < 64 * 64; e += 256) {
    int jj = e >> 6, dh = e & 63;
    ks[jj][dh] = k[((size_t)b * N_ + j0 + jj) * D_ + h * 64 + dh];
  }
  __syncthreads();
  int jj = threadIdx.x & 63;
  int ib = threadIdx.x >> 6;
  float acc[6] = {0.f, 0.f, 0.f, 0.f, 0.f, 0.f};
  for (int dh = 0; dh < 64; ++dh) {
    float kv = ks[jj][dh];
#pragma unroll
    for (int ii = 0; ii < 6; ++ii) acc[ii] += qs[ii * 4 + ib][dh] * kv;
  }
#pragma unroll
  for (int ii = 0; ii < 6; ++ii) {
    int i = ii * 4 + ib;
    dots[((size_t)(b * NS_ + i) * H_ + h) * N_ + j0 + jj] = acc[ii] * 0.125f;
  }
}

// ---------------- softmax over 192 (slot,head) per (b,j) -------------------
__global__ __launch_bounds__(256) void softmax_kernel(float* __restrict__ dots,
    float* __restrict__ asum, float* __restrict__ attn)
{
  int b = blockIdx.y;
  int j = blockIdx.x * 256 + threadIdx.x;
  size_t base = (size_t)b * TT_ * N_ + j;
  float m = -1e30f;
  for (int t = 0; t < TT_; ++t) m = fmaxf(m, dots[base + (size_t)t * N_]);
  float S = 0.f;
  for (int t = 0; t < TT_; ++t) S += __expf(dots[base + (size_t)t * N_] - m);
  float rinv = 1.f / S;
  float am[NS_];
#pragma unroll
  for (int i = 0; i < NS_; ++i) am[i] = 0.f;
  for (int t = 0; t < TT_; ++t) {
    float w = __expf(dots[base + (size_t)t * N_] - m) * rinv;
    dots[base + (size_t)t * N_] = w;
    am[t >> 3] += w;
    float wsum = w;
#pragma unroll
    for (int o = 1; o < 64; o <<= 1) wsum += __shfl_xor(wsum, o);
    if ((threadIdx.x & 63) == 0) atomicAdd(&asum[b * TT_ + t], wsum);
  }
  if (attn) {
    for (int i = 0; i < NS_; ++i)
      attn[((size_t)b * NS_ + i) * N_ + j] = am[i] * (1.f / H_);
  }
}

// ---------------- upd partial: 4-way j-split -------------------------------
__global__ __launch_bounds__(256) void upd_part_kernel(const float* __restrict__ a,
    const float* __restrict__ v, float* __restrict__ part)
{
  int bh = blockIdx.x;
  int c = blockIdx.y;
  int b = bh >> 3, h = bh & 7;
  __shared__ float vs[64][DH_ + 1];
  __shared__ float as[NS_][64];
  int dh = threadIdx.x & 63;
  int ib = threadIdx.x >> 6;
  float acc[6] = {0.f, 0.f, 0.f, 0.f, 0.f, 0.f};
  for (int j0 = c * 1024; j0 < (c + 1) * 1024; j0 += 64) {
    __syncthreads();
    for (int e = threadIdx.x; e < 64 * 64; e += 256) {
      int jj = e >> 6, d2 = e & 63;
      vs[jj][d2] = v[((size_t)b * N_ + j0 + jj) * D_ + h * 64 + d2];
    }
    for (int e = threadIdx.x; e < NS_ * 64; e += 256) {
      int i = e >> 6, jj = e & 63;
      as[i][jj] = a[((size_t)(b * NS_ + i) * H_ + h) * N_ + j0 + jj];
    }
    __syncthreads();
    for (int jj = 0; jj < 64; ++jj) {
      float vv = vs[jj][dh];
#pragma unroll
      for (int ii = 0; ii < 6; ++ii) acc[ii] += as[ii * 4 + ib][jj] * vv;
    }
  }
#pragma unroll
  for (int ii = 0; ii < 6; ++ii) {
    int i = ii * 4 + ib;
    part[((size_t)c * B_ * NS_ + b * NS_ + i) * D_ + h * 64 + dh] = acc[ii];
  }
}

// ---------------- upd finalize: -> hl operand for gi GEMM ------------------
__global__ __launch_bounds__(256) void upd_fin_kernel(const float* __restrict__ part,
    const float* __restrict__ vsum, const float* __restrict__ asum,
    unsigned short* __restrict__ updhl)
{
  int e = blockIdx.x * 256 + threadIdx.x;  // over B*NS*D
  int d = e & 511, bi = e >> 9;
  int b = bi / NS_, h = d >> 6, dh = d & 63;
  float s = part[e] + part[BNSD_ + e] + part[2 * BNSD_ + e] + part[3 * BNSD_ + e];
  float dnm = asum[bi * H_ + h] + (float)N_ * EPS_;
  float val = (s + EPS_ * vsum[(b * H_ + h) * 64 + dh]) / dnm;
  unsigned short hh = f2bf(val), ll = f2bf(val - bf2f(hh));
  updhl[(size_t)bi * 1024 + d] = hh;
  updhl[(size_t)bi * 1024 + 512 + d] = ll;
}

// ---------------- GRU elementwise ------------------------------------------
__global__ __launch_bounds__(256) void gru_kernel(const float* __restrict__ gi,
    const float* __restrict__ gh, const float* __restrict__ h, float* __restrict__ out)
{
  int e = blockIdx.x * 256 + threadIdx.x;
  int row = e >> 9, d = e & 511;
  const float* gir = gi + (size_t)row * 1536;
  const float* ghr = gh + (size_t)row * 1536;
  float ir = gir[d], iz = gir[512 + d], inn = gir[1024 + d];
  float hr = ghr[d], hz = ghr[512 + d], hn = ghr[1024 + d];
  float r = 1.f / (1.f + __expf(-(ir + hr)));
  float z = 1.f / (1.f + __expf(-(iz + hz)));
  float n = tanhf(inn + r * hn);
  out[e] = (1.f - z) * n + z * h[e];
}

// ---------------- LoRA -----------------------------------------------------
template<bool RELU_X>
__global__ __launch_bounds__(256) void lora_kernel(const float* __restrict__ x,
    const float* __restrict__ Am, const float* __restrict__ Bm,
    const int* __restrict__ idx, float* __restrict__ out, int Din, int Dout)
{
  int slot = blockIdx.x;
  int code = idx[slot];
  const float* xr = x + (size_t)slot * Din;
  const float* Ar = Am + (size_t)code * Din * R_;
  const float* Br = Bm + (size_t)code * R_ * Dout;
  float part[R_];
#pragma unroll
  for (int r = 0; r < R_; ++r) part[r] = 0.f;
  for (int d = threadIdx.x; d < Din; d += 256) {
    float xv = xr[d];
    if (RELU_X) xv = fmaxf(xv, 0.f);
#pragma unroll
    for (int r = 0; r < R_; ++r) part[r] += xv * Ar[(size_t)d * R_ + r];
  }
#pragma unroll
  for (int r = 0; r < R_; ++r)
#pragma unroll
    for (int o = 1; o < 64; o <<= 1) part[r] += __shfl_xor(part[r], o);
  __shared__ float tsh[4][R_];
  __shared__ float tfin[R_];
  int wave = threadIdx.x >> 6, lane = threadIdx.x & 63;
  if (lane == 0)
    for (int r = 0; r < R_; ++r) tsh[wave][r] = part[r];
  __syncthreads();
  if (threadIdx.x < R_)
    tfin[threadIdx.x] = (tsh[0][threadIdx.x] + tsh[1][threadIdx.x] +
                         tsh[2][threadIdx.x] + tsh[3][threadIdx.x]);
  __syncthreads();
  for (int c = threadIdx.x; c < Dout; c += 256) {
    float acc = 0.f;
#pragma unroll
    for (int r = 0; r < R_; ++r) acc += tfin[r] * Br[(size_t)r * Dout + c];
    out[(size_t)slot * Dout + c] += acc;
  }
}

// ---------------- finalize -------------------------------------------------
__global__ __launch_bounds__(256) void finalize_kernel(const float* __restrict__ slots,
    const int* __restrict__ idx, const float* __restrict__ commit, float* __restrict__ out)
{
  int t = blockIdx.x * 256 + threadIdx.x;
  if (t < B_ * NS_ * D_) out[t] = slots[t];
  if (t < B_ * NS_) {
    float iv = (float)idx[t];
    out[1769472 + t] = iv;
    out[1769857 + t] = iv;
  }
  if (t == 0) out[1769856] = commit[0];
}

// ---------------------------------------------------------------------------
extern "C" void kernel_launch(void* const* d_in, const int* in_sizes, int n_in,
                              void* d_out, int out_size, void* d_ws, size_t ws_size,
                              hipStream_t stream)
{
  const float* inputs  = (const float*)d_in[0];
  const float* cond    = (const float*)d_in[1];
  const float* Wq      = (const float*)d_in[2];
  const float* Wk      = (const float*)d_in[3];
  const float* Wv      = (const float*)d_in[4];
  const float* w_ih    = (const float*)d_in[5];
  const float* w_hh    = (const float*)d_in[6];
  const float* b_ih    = (const float*)d_in[7];
  const float* b_hh    = (const float*)d_in[8];
  const float* ln_in_g = (const float*)d_in[9];
  const float* ln_in_b = (const float*)d_in[10];
  const float* ln_s_g  = (const float*)d_in[11];
  const float* ln_s_b  = (const float*)d_in[12];
  const float* ln_f_g  = (const float*)d_in[13];
  const float* ln_f_b  = (const float*)d_in[14];
  const float* W1      = (const float*)d_in[15];
  const float* b1      = (const float*)d_in[16];
  const float* W2      = (const float*)d_in[17];
  const float* b2      = (const float*)d_in[18];
  const float* A1      = (const float*)d_in[19];
  const float* B1m     = (const float*)d_in[20];
  const float* A2      = (const float*)d_in[21];
  const float* B2m     = (const float*)d_in[22];
  const float* codebook= (const float*)d_in[23];

  float* out = (float*)d_out;
  float* ws  = (float*)d_ws;

  // ---- region 0 (33.5M fslots): phase A = xhat_hl; loop = dots + scratch --
  unsigned short* xhat_hl = (unsigned short*)ws;
  float* dots    = ws;                         // [0, 12582912)
  float* updpart = ws + 12582912;              // 786432
  float* gpart   = ws + 13369344;              // 3145728
  unsigned short* WqT  = (unsigned short*)(ws + 16515072);  // 512x1536 u16
  unsigned short* wihT = (unsigned short*)(ws + 16908288);  // 1536x1536
  unsigned short* whhT = (unsigned short*)(ws + 18087936);  // 1536x1536
  unsigned short* W1T  = (unsigned short*)(ws + 19267584);  // 2048x1536
  unsigned short* W2T  = (unsigned short*)(ws + 20840448);  // 512x6144
  unsigned short* s_hl    = (unsigned short*)(ws + 22413312);  // 384x1024
  unsigned short* slotshl = (unsigned short*)(ws + 22609920);  // 384x1024
  unsigned short* updhl   = (unsigned short*)(ws + 22806528);  // 384x1024
  unsigned short* h1hl    = (unsigned short*)(ws + 23003136);  // 384x4096

  size_t off = 33554432;
  float* kbuf = ws + off; off += 33554432;
  float* vbuf = ws + off; off += 33554432;
  unsigned short* WkT = (unsigned short*)(ws + off); off += 393216;
  unsigned short* WvT = (unsigned short*)(ws + off); off += 393216;
  float* slots_cur = ws + off; off += BNSD_;
  float* slots_gru = ws + off; off += BNSD_;
  float* sbuf      = ws + off; off += BNSD_;
  float* qb        = ws + off; off += BNSD_;
  float* gib       = ws + off; off += B_ * NS_ * 3 * D_;
  float* ghb       = ws + off; off += B_ * NS_ * 3 * D_;
  float* h1b       = ws + off; off += B_ * NS_ * 4 * D_;
  float* vsumb     = ws + off; off += B_ * H_ * DH_;
  float* asumb     = ws + off; off += B_ * TT_;
  float* commitb   = ws + off; off += 1;
  int*   idxb      = (int*)(ws + off); off += B_ * NS_;

  // ---- phase A: LN(inputs)->hl, k/v MFMA, then weight prep in region 0 ----
  ln_hl_kernel<<<B_ * N_, 128, 0, stream>>>(inputs, ln_in_g, ln_in_b, xhat_hl);
  wtrans_g<<<dim3(8, 8), 256, 0, stream>>>(Wk, WkT, 512, 512);
  wtrans_g<<<dim3(8, 8), 256, 0, stream>>>(Wv, WvT, 512, 512);
  gemm_kv<<<dim3(4, 512), 256, 0, stream>>>(xhat_hl, WkT, kbuf);
  gemm_kv<<<dim3(4, 512), 256, 0, stream>>>(xhat_hl, WvT, vbuf);
  vsum_kernel<<<B_ * H_, 256, 0, stream>>>(vbuf, vsumb);
  // xhat region now dead -> safe to write weights/operands there
  wtrans_g<<<dim3(8, 8), 256, 0, stream>>>(Wq, WqT, 512, 512);
  wsplit_nm<<<3072, 256, 0, stream>>>(w_ih, wihT, 512, 1536 * 512);
  wsplit_nm<<<3072, 256, 0, stream>>>(w_hh, whhT, 512, 1536 * 512);
  wtrans_g<<<dim3(32, 8), 256, 0, stream>>>(W1, W1T, 512, 2048);
  wtrans_g<<<dim3(8, 32), 256, 0, stream>>>(W2, W2T, 2048, 512);
  f32tohl_kernel<<<768, 256, 0, stream>>>(cond, slots_cur, slotshl, BNSD_);

  // ---- phase B: 3 slot-attention iterations ----
  for (int it = 0; it < 3; ++it) {
    if (it > 0) {
      hipMemsetAsync(commitb, 0, sizeof(float), stream);
      vq_kernel<<<B_ * NS_, 256, 0, stream>>>(slots_cur, codebook, idxb, commitb);
    }
    ln_dual_kernel<<<B_ * NS_, 128, 0, stream>>>(slots_cur, ln_s_g, ln_s_b, sbuf, s_hl);
    // q = s @ Wq : N=512, K=512, Z=4, S=6
    gemm_sp<<<dim3(8, 3, 4), 256, 0, stream>>>(s_hl, WqT, gpart, 512, 512, 6);
    redep<false, false, false><<<768, 256, 0, stream>>>(gpart, nullptr, nullptr, qb, nullptr, 512, 4);
    dots_kernel<<<dim3(N_ / 64, B_ * H_), 256, 0, stream>>>(qb, kbuf, dots);
    hipMemsetAsync(asumb, 0, (size_t)B_ * TT_ * sizeof(float), stream);
    softmax_kernel<<<dim3(N_ / 256, B_), 256, 0, stream>>>(
        dots, asumb, (it == 2) ? (out + (size_t)BNSD_) : nullptr);
    upd_part_kernel<<<dim3(B_ * H_, 4), 256, 0, stream>>>(dots, vbuf, updpart);
    upd_fin_kernel<<<BNSD_ / 256, 256, 0, stream>>>(updpart, vsumb, asumb, updhl);
    // gi = upd @ w_ih.T + b_ih : N=1536, K=512, Z=4, S=6
    gemm_sp<<<dim3(24, 3, 4), 256, 0, stream>>>(updhl, wihT, gpart, 1536, 512, 6);
    redep<true, false, false><<<2304, 256, 0, stream>>>(gpart, b_ih, nullptr, gib, nullptr, 1536, 4);
    // gh = slots @ w_hh.T + b_hh
    gemm_sp<<<dim3(24, 3, 4), 256, 0, stream>>>(slotshl, whhT, gpart, 1536, 512, 6);
    redep<true, false, false><<<2304, 256, 0, stream>>>(gpart, b_hh, nullptr, ghb, nullptr, 1536, 4);
    gru_kernel<<<BNSD_ / 256, 256, 0, stream>>>(gib, ghb, slots_cur, slots_gru);
    ln_dual_kernel<<<B_ * NS_, 128, 0, stream>>>(slots_gru, ln_f_g, ln_f_b, sbuf, s_hl);
    // h1 = s2 @ W1 + b1 : N=2048, K=512, Z=4, S=6
    gemm_sp<<<dim3(32, 3, 4), 256, 0, stream>>>(s_hl, W1T, gpart, 2048, 512, 6);
    redep<true, false, false><<<3072, 256, 0, stream>>>(gpart, b1, nullptr, h1b, nullptr, 2048, 4);
    if (it > 0)
      lora_kernel<false><<<B_ * NS_, 256, 0, stream>>>(sbuf, A1, B1m, idxb, h1b, D_, 4 * D_);
    reluhl_kernel<<<3072, 256, 0, stream>>>(h1b, h1hl);
    // out = relu(h1) @ W2 + b2 + slots_gru : N=512, K=2048, Z=8, S=12
    gemm_sp<<<dim3(8, 3, 8), 256, 0, stream>>>(h1hl, W2T, gpart, 512, 2048, 12);
    redep<true, true, true><<<768, 256, 0, stream>>>(gpart, b2, slots_gru, slots_cur, slotshl, 512, 8);
    if (it > 0)
      lora_kernel<true><<<B_ * NS_, 256, 0, stream>>>(h1b, A2, B2m, idxb, slots_cur, 4 * D_, D_);
    if (it == 1)   // refresh hl after lora2 (needed by next iter's gh GEMM)
      f32tohl_kernel<<<768, 256, 0, stream>>>(slots_cur, nullptr, slotshl, BNSD_);
  }

  finalize_kernel<<<BNSD_ / 256, 256, 0, stream>>>(slots_cur, idxb, commitb, out);
}

// Round 5
// 1653.754 us; speedup vs baseline: 3.7499x; 1.2111x over previous
//
#include <hip/hip_runtime.h>
#include <hip/hip_bf16.h>
#include <math.h>

// ---------------------------------------------------------------------------
// SlotAttentionMod: B=16 N=4096 NS=24 D=512 H=8 DH=64 K=512 R=8 ITERS=3
// Round 5: softmax restructured (4-way t-split, 1024 blocks, no atomics);
// asum via dedicated coalesced row-sum kernel; upd_part 8-way j-split.
// ---------------------------------------------------------------------------

#define B_ 16
#define N_ 4096
#define NS_ 24
#define D_ 512
#define H_ 8
#define DH_ 64
#define KC_ 512
#define R_ 8
#define TT_ (NS_*H_)
#define EPS_ 1e-8f
#define BNSD_ (B_*NS_*D_)   // 196608
#define M_ 384              // B*NS

typedef unsigned short u16x8 __attribute__((ext_vector_type(8)));
typedef short s16x8 __attribute__((ext_vector_type(8)));
typedef float f32x4 __attribute__((ext_vector_type(4)));

__device__ inline unsigned short f2bf(float f) {
  unsigned int u = __float_as_uint(f);
  u += 0x7FFFu + ((u >> 16) & 1u);          // RNE
  return (unsigned short)(u >> 16);
}
__device__ inline float bf2f(unsigned short h) {
  return __uint_as_float(((unsigned int)h) << 16);
}

// ---------------- LayerNorm -> split-bf16 out [row][1024] (hi|lo) ----------
__global__ __launch_bounds__(128) void ln_hl_kernel(const float* __restrict__ X,
    const float* __restrict__ g, const float* __restrict__ bb,
    unsigned short* __restrict__ Y)
{
  int row = blockIdx.x;
  const float* xr = X + (size_t)row * D_;
  int t = threadIdx.x;
  float lv[4];
#pragma unroll
  for (int i = 0; i < 4; ++i) lv[i] = xr[t + 128 * i];
  float s = lv[0] + lv[1] + lv[2] + lv[3];
#pragma unroll
  for (int o = 1; o < 64; o <<= 1) s += __shfl_xor(s, o);
  __shared__ float sh[2], sh2[2];
  if ((t & 63) == 0) sh[t >> 6] = s;
  __syncthreads();
  float mean = (sh[0] + sh[1]) * (1.f / D_);
  float q = 0.f;
#pragma unroll
  for (int i = 0; i < 4; ++i) { float d = lv[i] - mean; q += d * d; }
#pragma unroll
  for (int o = 1; o < 64; o <<= 1) q += __shfl_xor(q, o);
  if ((t & 63) == 0) sh2[t >> 6] = q;
  __syncthreads();
  float var = (sh2[0] + sh2[1]) * (1.f / D_);
  float rstd = 1.0f / sqrtf(var + 1e-5f);
#pragma unroll
  for (int i = 0; i < 4; ++i) {
    int d = t + 128 * i;
    float y = (lv[i] - mean) * rstd * g[d] + bb[d];
    unsigned short h = f2bf(y);
    unsigned short l = f2bf(y - bf2f(h));
    Y[(size_t)row * 1024 + d] = h;
    Y[(size_t)row * 1024 + 512 + d] = l;
  }
}

// ---------------- LayerNorm -> f32 AND hl outputs --------------------------
__global__ __launch_bounds__(128) void ln_dual_kernel(const float* __restrict__ X,
    const float* __restrict__ g, const float* __restrict__ bb,
    float* __restrict__ Yf, unsigned short* __restrict__ Yhl)
{
  int row = blockIdx.x;
  const float* xr = X + (size_t)row * D_;
  int t = threadIdx.x;
  float lv[4];
#pragma unroll
  for (int i = 0; i < 4; ++i) lv[i] = xr[t + 128 * i];
  float s = lv[0] + lv[1] + lv[2] + lv[3];
#pragma unroll
  for (int o = 1; o < 64; o <<= 1) s += __shfl_xor(s, o);
  __shared__ float sh[2], sh2[2];
  if ((t & 63) == 0) sh[t >> 6] = s;
  __syncthreads();
  float mean = (sh[0] + sh[1]) * (1.f / D_);
  float q = 0.f;
#pragma unroll
  for (int i = 0; i < 4; ++i) { float d = lv[i] - mean; q += d * d; }
#pragma unroll
  for (int o = 1; o < 64; o <<= 1) q += __shfl_xor(q, o);
  if ((t & 63) == 0) sh2[t >> 6] = q;
  __syncthreads();
  float var = (sh2[0] + sh2[1]) * (1.f / D_);
  float rstd = 1.0f / sqrtf(var + 1e-5f);
#pragma unroll
  for (int i = 0; i < 4; ++i) {
    int d = t + 128 * i;
    float y = (lv[i] - mean) * rstd * g[d] + bb[d];
    Yf[(size_t)row * D_ + d] = y;
    unsigned short h = f2bf(y);
    unsigned short l = f2bf(y - bf2f(h));
    Yhl[(size_t)row * 1024 + d] = h;
    Yhl[(size_t)row * 1024 + 512 + d] = l;
  }
}

// ---------------- generalized weight transpose+split -----------------------
// W [K][N] f32 -> WT [N][3K] u16: [0:K]=hi, [K:2K]=hi, [2K:3K]=lo
__global__ __launch_bounds__(256) void wtrans_g(const float* __restrict__ W,
    unsigned short* __restrict__ WT, int K, int N)
{
  __shared__ float t[64][65];
  int n0 = blockIdx.x * 64, k0 = blockIdx.y * 64;
  for (int e = threadIdx.x; e < 4096; e += 256) {
    int kk = e >> 6, nn = e & 63;
    t[kk][nn] = W[(size_t)(k0 + kk) * N + n0 + nn];
  }
  __syncthreads();
  for (int e = threadIdx.x; e < 4096; e += 256) {
    int nn = e >> 6, kk = e & 63;
    float v = t[kk][nn];
    unsigned short h = f2bf(v);
    unsigned short l = f2bf(v - bf2f(h));
    size_t base = (size_t)(n0 + nn) * 3 * K + (k0 + kk);
    WT[base] = h; WT[base + K] = h; WT[base + 2 * K] = l;
  }
}

// ---------------- split (no transpose): W [N][K] -> WT [N][3K] -------------
__global__ __launch_bounds__(256) void wsplit_nm(const float* __restrict__ W,
    unsigned short* __restrict__ WT, int K, int total)
{
  int e = blockIdx.x * 256 + threadIdx.x;
  if (e >= total) return;
  int n = e / K, k = e % K;
  float v = W[e];
  unsigned short h = f2bf(v);
  unsigned short l = f2bf(v - bf2f(h));
  size_t base = (size_t)n * 3 * K + k;
  WT[base] = h; WT[base + K] = h; WT[base + 2 * K] = l;
}

// ---------------- f32 -> hl (optional f32 copy) ----------------------------
__global__ __launch_bounds__(256) void f32tohl_kernel(const float* __restrict__ X,
    float* __restrict__ Cout, unsigned short* __restrict__ HL, int total)
{
  int e = blockIdx.x * 256 + threadIdx.x;
  if (e >= total) return;
  float v = X[e];
  if (Cout) Cout[e] = v;
  int m = e >> 9, d = e & 511;
  unsigned short h = f2bf(v);
  unsigned short l = f2bf(v - bf2f(h));
  HL[(size_t)m * 1024 + d] = h;
  HL[(size_t)m * 1024 + 512 + d] = l;
}

// ---------------- relu(h1) -> hl [m][4096] ---------------------------------
__global__ __launch_bounds__(256) void reluhl_kernel(const float* __restrict__ X,
    unsigned short* __restrict__ HL)
{
  int e = blockIdx.x * 256 + threadIdx.x;   // < 384*2048
  float v = fmaxf(X[e], 0.f);
  int m = e >> 11, d = e & 2047;
  unsigned short h = f2bf(v);
  unsigned short l = f2bf(v - bf2f(h));
  HL[(size_t)m * 4096 + d] = h;
  HL[(size_t)m * 4096 + 2048 + d] = l;
}

// ---------------- split-bf16 MFMA GEMM: k/v (128x128 tile) -----------------
__global__ __launch_bounds__(256) void gemm_kv(
    const unsigned short* __restrict__ A, const unsigned short* __restrict__ BT,
    float* __restrict__ C)
{
  __shared__ unsigned short As[128 * 64];
  __shared__ unsigned short Bs[128 * 64];
  const int tid = threadIdx.x;
  const int lane = tid & 63, wid = tid >> 6;
  const int wm = wid >> 1, wn = wid & 1;
  const int g = lane >> 4, r16 = lane & 15;
  const int m0 = blockIdx.y * 128, n0 = blockIdx.x * 128;

  f32x4 acc[4][4] = {};
  u16x8 ra[4], rb[4];
  int srow[4], sj[4];
#pragma unroll
  for (int i = 0; i < 4; ++i) {
    int s = tid + (i << 8);
    srow[i] = s >> 3;
    sj[i] = (s & 7) ^ (srow[i] & 7);
  }
#pragma unroll
  for (int i = 0; i < 4; ++i) {
    ra[i] = *(const u16x8*)(A + (size_t)(m0 + srow[i]) * 1024 + (sj[i] << 3));
    rb[i] = *(const u16x8*)(BT + (size_t)(n0 + srow[i]) * 1536 + (sj[i] << 3));
  }
  u16x8* Asw = (u16x8*)As;
  u16x8* Bsw = (u16x8*)Bs;
  const s16x8* Asv = (const s16x8*)As;
  const s16x8* Bsv = (const s16x8*)Bs;

  for (int kk = 0; kk < 24; ++kk) {
    __syncthreads();
#pragma unroll
    for (int i = 0; i < 4; ++i) {
      Asw[tid + (i << 8)] = ra[i];
      Bsw[tid + (i << 8)] = rb[i];
    }
    __syncthreads();
    if (kk + 1 < 24) {
      int k2 = kk + 1;
      int acol = ((k2 < 16) ? k2 : (k2 - 16)) * 64;
      int bcol = k2 * 64;
#pragma unroll
      for (int i = 0; i < 4; ++i) {
        ra[i] = *(const u16x8*)(A + (size_t)(m0 + srow[i]) * 1024 + acol + (sj[i] << 3));
        rb[i] = *(const u16x8*)(BT + (size_t)(n0 + srow[i]) * 1536 + bcol + (sj[i] << 3));
      }
    }
#pragma unroll
    for (int kh = 0; kh < 2; ++kh) {
      s16x8 af[4], bfr[4];
      int j = kh * 4 + g;
#pragma unroll
      for (int mi = 0; mi < 4; ++mi) {
        int m = wm * 64 + mi * 16 + r16;
        af[mi] = Asv[m * 8 + (j ^ (m & 7))];
      }
#pragma unroll
      for (int ni = 0; ni < 4; ++ni) {
        int n = wn * 64 + ni * 16 + r16;
        bfr[ni] = Bsv[n * 8 + (j ^ (n & 7))];
      }
#pragma unroll
      for (int mi = 0; mi < 4; ++mi)
#pragma unroll
        for (int ni = 0; ni < 4; ++ni)
          acc[mi][ni] = __builtin_amdgcn_mfma_f32_16x16x32_bf16(
              af[mi], bfr[ni], acc[mi][ni], 0, 0, 0);
    }
  }
#pragma unroll
  for (int mi = 0; mi < 4; ++mi) {
    int mrow = m0 + wm * 64 + mi * 16 + g * 4;
#pragma unroll
    for (int ni = 0; ni < 4; ++ni) {
      int ncol = n0 + wn * 64 + ni * 16 + r16;
#pragma unroll
      for (int j = 0; j < 4; ++j)
        C[(size_t)(mrow + j) * 512 + ncol] = acc[mi][ni][j];
    }
  }
}

// ---------------- split-bf16 MFMA small GEMM with split-K ------------------
// A [M][2K] hl, WT [N][3K], part [Z][384][N]. 128x64 tile, steps of 64 K'.
__global__ __launch_bounds__(256) void gemm_sp(
    const unsigned short* __restrict__ A, const unsigned short* __restrict__ WT,
    float* __restrict__ part, int N, int K, int S)
{
  __shared__ unsigned short As[128 * 64];
  __shared__ unsigned short Bs[64 * 64];
  const int tid = threadIdx.x;
  const int lane = tid & 63, wid = tid >> 6;
  const int wm = wid >> 1, wn = wid & 1;
  const int g = lane >> 4, r16 = lane & 15;
  const int n0 = blockIdx.x * 64, m0 = blockIdx.y * 128, z = blockIdx.z;
  const int twoK = 2 * K;
  const size_t ldb = (size_t)3 * K;

  f32x4 acc[4][2] = {};
  u16x8 ra[4], rb[2];
  int arow[4], aj[4], brow[2], bj[2];
#pragma unroll
  for (int i = 0; i < 4; ++i) {
    int s = tid + (i << 8);
    arow[i] = s >> 3; aj[i] = (s & 7) ^ (arow[i] & 7);
  }
#pragma unroll
  for (int i = 0; i < 2; ++i) {
    int s = tid + (i << 8);
    brow[i] = s >> 3; bj[i] = (s & 7) ^ (brow[i] & 7);
  }
  const int s0 = z * S;
  {
    int c = s0 * 64;
    int ac = (c < twoK) ? c : c - twoK;
#pragma unroll
    for (int i = 0; i < 4; ++i)
      ra[i] = *(const u16x8*)(A + (size_t)(m0 + arow[i]) * twoK + ac + (aj[i] << 3));
#pragma unroll
    for (int i = 0; i < 2; ++i)
      rb[i] = *(const u16x8*)(WT + (size_t)(n0 + brow[i]) * ldb + c + (bj[i] << 3));
  }
  u16x8* Asw = (u16x8*)As;
  u16x8* Bsw = (u16x8*)Bs;
  const s16x8* Asv = (const s16x8*)As;
  const s16x8* Bsv = (const s16x8*)Bs;

  for (int st = 0; st < S; ++st) {
    __syncthreads();
#pragma unroll
    for (int i = 0; i < 4; ++i) Asw[tid + (i << 8)] = ra[i];
#pragma unroll
    for (int i = 0; i < 2; ++i) Bsw[tid + (i << 8)] = rb[i];
    __syncthreads();
    if (st + 1 < S) {
      int c = (s0 + st + 1) * 64;
      int ac = (c < twoK) ? c : c - twoK;
#pragma unroll
      for (int i = 0; i < 4; ++i)
        ra[i] = *(const u16x8*)(A + (size_t)(m0 + arow[i]) * twoK + ac + (aj[i] << 3));
#pragma unroll
      for (int i = 0; i < 2; ++i)
        rb[i] = *(const u16x8*)(WT + (size_t)(n0 + brow[i]) * ldb + c + (bj[i] << 3));
    }
#pragma unroll
    for (int kh = 0; kh < 2; ++kh) {
      int j = kh * 4 + g;
      s16x8 af[4], bf2v[2];
#pragma unroll
      for (int mi = 0; mi < 4; ++mi) {
        int m = wm * 64 + mi * 16 + r16;
        af[mi] = Asv[m * 8 + (j ^ (m & 7))];
      }
#pragma unroll
      for (int ni = 0; ni < 2; ++ni) {
        int n = wn * 32 + ni * 16 + r16;
        bf2v[ni] = Bsv[n * 8 + (j ^ (n & 7))];
      }
#pragma unroll
      for (int mi = 0; mi < 4; ++mi)
#pragma unroll
        for (int ni = 0; ni < 2; ++ni)
          acc[mi][ni] = __builtin_amdgcn_mfma_f32_16x16x32_bf16(
              af[mi], bf2v[ni], acc[mi][ni], 0, 0, 0);
    }
  }
  size_t zb = (size_t)z * M_ * N;
#pragma unroll
  for (int mi = 0; mi < 4; ++mi) {
    int mr = m0 + wm * 64 + mi * 16 + g * 4;
#pragma unroll
    for (int ni = 0; ni < 2; ++ni) {
      int nc = n0 + wn * 32 + ni * 16 + r16;
#pragma unroll
      for (int j2 = 0; j2 < 4; ++j2)
        part[zb + (size_t)(mr + j2) * N + nc] = acc[mi][ni][j2];
    }
  }
}

// ---------------- reduce partials + epilogue -------------------------------
template<bool BIAS, bool RES, bool WHL>
__global__ __launch_bounds__(256) void redep(const float* __restrict__ part,
    const float* __restrict__ bias, const float* __restrict__ res,
    float* __restrict__ C, unsigned short* __restrict__ HL, int N, int Z)
{
  int e = blockIdx.x * 256 + threadIdx.x;   // < 384*N
  size_t MN = (size_t)M_ * N;
  float v = 0.f;
  for (int z = 0; z < Z; ++z) v += part[(size_t)z * MN + e];
  int m = e / N, n = e - m * N;
  if (BIAS) v += bias[n];
  if (RES) v += res[e];
  C[e] = v;
  if (WHL) {
    unsigned short h = f2bf(v), l = f2bf(v - bf2f(h));
    HL[(size_t)m * 2 * N + n] = h;
    HL[(size_t)m * 2 * N + N + n] = l;
  }
}

// ---------------- vsum[b,h,dh] = sum_j v[b,j,h,dh] -------------------------
__global__ __launch_bounds__(256) void vsum_kernel(const float* __restrict__ v,
                                                   float* __restrict__ vsum)
{
  int b = blockIdx.x >> 3, h = blockIdx.x & 7;
  int dh = threadIdx.x & 63, w = threadIdx.x >> 6;
  float acc = 0.f;
  for (int j = w * (N_ / 4); j < (w + 1) * (N_ / 4); ++j)
    acc += v[((size_t)b * N_ + j) * D_ + h * 64 + dh];
  __shared__ float sh[4][64];
  sh[w][dh] = acc;
  __syncthreads();
  if (w == 0)
    vsum[(size_t)blockIdx.x * 64 + dh] = sh[0][dh] + sh[1][dh] + sh[2][dh] + sh[3][dh];
}

// ---------------- VQ -------------------------------------------------------
__global__ __launch_bounds__(256) void vq_kernel(const float* __restrict__ slots,
    const float* __restrict__ cb, int* __restrict__ idx, float* __restrict__ commit)
{
  __shared__ float ss[D_];
  int slot = blockIdx.x;
  const float* sr = slots + (size_t)slot * D_;
  for (int d = threadIdx.x; d < D_; d += 256) ss[d] = sr[d];
  __syncthreads();
  float best = 1e30f; int bi = 0;
  for (int c = threadIdx.x; c < KC_; c += 256) {
    const float* cr = cb + (size_t)c * D_;
    float d2 = 0.f;
    for (int d = 0; d < D_; ++d) { float df = ss[d] - cr[d]; d2 += df * df; }
    if (d2 < best) { best = d2; bi = c; }
  }
  __shared__ float rb[256]; __shared__ int ri[256];
  rb[threadIdx.x] = best; ri[threadIdx.x] = bi;
  __syncthreads();
  for (int s = 128; s > 0; s >>= 1) {
    if (threadIdx.x < s) {
      float ob = rb[threadIdx.x + s]; int oi = ri[threadIdx.x + s];
      if (ob < rb[threadIdx.x] || (ob == rb[threadIdx.x] && oi < ri[threadIdx.x])) {
        rb[threadIdx.x] = ob; ri[threadIdx.x] = oi;
      }
    }
    __syncthreads();
  }
  if (threadIdx.x == 0) {
    idx[slot] = ri[0];
    atomicAdd(commit, rb[0] * (1.f / (B_ * NS_ * D_)));
  }
}

// ---------------- dots[b, i*8+h, j] ----------------------------------------
__global__ __launch_bounds__(256) void dots_kernel(const float* __restrict__ q,
    const float* __restrict__ k, float* __restrict__ dots)
{
  int b = blockIdx.y >> 3, h = blockIdx.y & 7;
  int j0 = blockIdx.x * 64;
  __shared__ float qs[NS_][DH_];
  __shared__ float ks[64][DH_ + 1];
  for (int e = threadIdx.x; e < NS_ * DH_; e += 256) {
    int i = e >> 6, dh = e & 63;
    qs[i][dh] = q[(size_t)(b * NS_ + i) * D_ + h * 64 + dh];
  }
  for (int e = threadIdx.x; e < 64 * 64; e += 256) {
    int jj = e >> 6, dh = e & 63;
    ks[jj][dh] = k[((size_t)b * N_ + j0 + jj) * D_ + h * 64 + dh];
  }
  __syncthreads();
  int jj = threadIdx.x & 63;
  int ib = threadIdx.x >> 6;
  float acc[6] = {0.f, 0.f, 0.f, 0.f, 0.f, 0.f};
  for (int dh = 0; dh < 64; ++dh) {
    float kv = ks[jj][dh];
#pragma unroll
    for (int ii = 0; ii < 6; ++ii) acc[ii] += qs[ii * 4 + ib][dh] * kv;
  }
#pragma unroll
  for (int ii = 0; ii < 6; ++ii) {
    int i = ii * 4 + ib;
    dots[((size_t)(b * NS_ + i) * H_ + h) * N_ + j0 + jj] = acc[ii] * 0.125f;
  }
}

// ---------------- softmax over 192 (slot,head) per (b,j) -------------------
// 4-way t-split: block = 64 j's x 4 t-groups (48 t's each = 6 whole slots).
// No atomics; asum computed by asum_kernel afterwards.
__global__ __launch_bounds__(256) void softmax_kernel(float* __restrict__ dots,
    float* __restrict__ attn)
{
  int b = blockIdx.y;
  int jj = threadIdx.x & 63;
  int tg = threadIdx.x >> 6;
  int j = blockIdx.x * 64 + jj;
  size_t base = (size_t)b * TT_ * N_ + j;
  const int t0 = tg * 48;
  __shared__ float red[4][64];

  float m = -1e30f;
  for (int t = t0; t < t0 + 48; ++t)
    m = fmaxf(m, dots[base + (size_t)t * N_]);
  red[tg][jj] = m;
  __syncthreads();
  m = fmaxf(fmaxf(red[0][jj], red[1][jj]), fmaxf(red[2][jj], red[3][jj]));
  __syncthreads();

  float S = 0.f;
  for (int t = t0; t < t0 + 48; ++t)
    S += __expf(dots[base + (size_t)t * N_] - m);
  red[tg][jj] = S;
  __syncthreads();
  S = red[0][jj] + red[1][jj] + red[2][jj] + red[3][jj];
  float rinv = 1.f / S;

  for (int s6 = 0; s6 < 6; ++s6) {
    float am = 0.f;
#pragma unroll
    for (int r = 0; r < 8; ++r) {
      int t = t0 + s6 * 8 + r;
      float w = __expf(dots[base + (size_t)t * N_] - m) * rinv;
      dots[base + (size_t)t * N_] = w;
      am += w;
    }
    if (attn)
      attn[((size_t)b * NS_ + (tg * 6 + s6)) * N_ + j] = am * (1.f / H_);
  }
}

// ---------------- asum[row] = sum_j w[row][j], row = b*TT + t --------------
__global__ __launch_bounds__(256) void asum_kernel(const float* __restrict__ w,
                                                   float* __restrict__ asum)
{
  int row = blockIdx.x;
  const float4* r4 = (const float4*)(w + (size_t)row * N_);
  float s = 0.f;
  for (int p = threadIdx.x; p < N_ / 4; p += 256) {
    float4 v = r4[p];
    s += v.x + v.y + v.z + v.w;
  }
#pragma unroll
  for (int o = 1; o < 64; o <<= 1) s += __shfl_xor(s, o);
  __shared__ float sh[4];
  if ((threadIdx.x & 63) == 0) sh[threadIdx.x >> 6] = s;
  __syncthreads();
  if (threadIdx.x == 0) asum[row] = sh[0] + sh[1] + sh[2] + sh[3];
}

// ---------------- upd partial: 8-way j-split -------------------------------
__global__ __launch_bounds__(256) void upd_part_kernel(const float* __restrict__ a,
    const float* __restrict__ v, float* __restrict__ part)
{
  int bh = blockIdx.x;
  int c = blockIdx.y;             // 0..7
  int b = bh >> 3, h = bh & 7;
  __shared__ float vs[64][DH_ + 1];
  __shared__ float as[NS_][64];
  int dh = threadIdx.x & 63;
  int ib = threadIdx.x >> 6;
  float acc[6] = {0.f, 0.f, 0.f, 0.f, 0.f, 0.f};
  for (int j0 = c * 512; j0 < (c + 1) * 512; j0 += 64) {
    __syncthreads();
    for (int e = threadIdx.x; e < 64 * 64; e += 256) {
      int jj = e >> 6, d2 = e & 63;
      vs[jj][d2] = v[((size_t)b * N_ + j0 + jj) * D_ + h * 64 + d2];
    }
    for (int e = threadIdx.x; e < NS_ * 64; e += 256) {
      int i = e >> 6, jj = e & 63;
      as[i][jj] = a[((size_t)(b * NS_ + i) * H_ + h) * N_ + j0 + jj];
    }
    __syncthreads();
    for (int jj = 0; jj < 64; ++jj) {
      float vv = vs[jj][dh];
#pragma unroll
      for (int ii = 0; ii < 6; ++ii) acc[ii] += as[ii * 4 + ib][jj] * vv;
    }
  }
#pragma unroll
  for (int ii = 0; ii < 6; ++ii) {
    int i = ii * 4 + ib;
    part[((size_t)c * B_ * NS_ + b * NS_ + i) * D_ + h * 64 + dh] = acc[ii];
  }
}

// ---------------- upd finalize: -> hl operand for gi GEMM ------------------
__global__ __launch_bounds__(256) void upd_fin_kernel(const float* __restrict__ part,
    const float* __restrict__ vsum, const float* __restrict__ asum,
    unsigned short* __restrict__ updhl)
{
  int e = blockIdx.x * 256 + threadIdx.x;  // over B*NS*D
  int d = e & 511, bi = e >> 9;
  int b = bi / NS_, h = d >> 6, dh = d & 63;
  float s = 0.f;
#pragma unroll
  for (int z = 0; z < 8; ++z) s += part[(size_t)z * BNSD_ + e];
  float dnm = asum[bi * H_ + h] + (float)N_ * EPS_;
  float val = (s + EPS_ * vsum[(b * H_ + h) * 64 + dh]) / dnm;
  unsigned short hh = f2bf(val), ll = f2bf(val - bf2f(hh));
  updhl[(size_t)bi * 1024 + d] = hh;
  updhl[(size_t)bi * 1024 + 512 + d] = ll;
}

// ---------------- GRU elementwise ------------------------------------------
__global__ __launch_bounds__(256) void gru_kernel(const float* __restrict__ gi,
    const float* __restrict__ gh, const float* __restrict__ h, float* __restrict__ out)
{
  int e = blockIdx.x * 256 + threadIdx.x;
  int row = e >> 9, d = e & 511;
  const float* gir = gi + (size_t)row * 1536;
  const float* ghr = gh + (size_t)row * 1536;
  float ir = gir[d], iz = gir[512 + d], inn = gir[1024 + d];
  float hr = ghr[d], hz = ghr[512 + d], hn = ghr[1024 + d];
  float r = 1.f / (1.f + __expf(-(ir + hr)));
  float z = 1.f / (1.f + __expf(-(iz + hz)));
  float n = tanhf(inn + r * hn);
  out[e] = (1.f - z) * n + z * h[e];
}

// ---------------- LoRA -----------------------------------------------------
template<bool RELU_X>
__global__ __launch_bounds__(256) void lora_kernel(const float* __restrict__ x,
    const float* __restrict__ Am, const float* __restrict__ Bm,
    const int* __restrict__ idx, float* __restrict__ out, int Din, int Dout)
{
  int slot = blockIdx.x;
  int code = idx[slot];
  const float* xr = x + (size_t)slot * Din;
  const float* Ar = Am + (size_t)code * Din * R_;
  const float* Br = Bm + (size_t)code * R_ * Dout;
  float part[R_];
#pragma unroll
  for (int r = 0; r < R_; ++r) part[r] = 0.f;
  for (int d = threadIdx.x; d < Din; d += 256) {
    float xv = xr[d];
    if (RELU_X) xv = fmaxf(xv, 0.f);
#pragma unroll
    for (int r = 0; r < R_; ++r) part[r] += xv * Ar[(size_t)d * R_ + r];
  }
#pragma unroll
  for (int r = 0; r < R_; ++r)
#pragma unroll
    for (int o = 1; o < 64; o <<= 1) part[r] += __shfl_xor(part[r], o);
  __shared__ float tsh[4][R_];
  __shared__ float tfin[R_];
  int wave = threadIdx.x >> 6, lane = threadIdx.x & 63;
  if (lane == 0)
    for (int r = 0; r < R_; ++r) tsh[wave][r] = part[r];
  __syncthreads();
  if (threadIdx.x < R_)
    tfin[threadIdx.x] = (tsh[0][threadIdx.x] + tsh[1][threadIdx.x] +
                         tsh[2][threadIdx.x] + tsh[3][threadIdx.x]);
  __syncthreads();
  for (int c = threadIdx.x; c < Dout; c += 256) {
    float acc = 0.f;
#pragma unroll
    for (int r = 0; r < R_; ++r) acc += tfin[r] * Br[(size_t)r * Dout + c];
    out[(size_t)slot * Dout + c] += acc;
  }
}

// ---------------- finalize -------------------------------------------------
__global__ __launch_bounds__(256) void finalize_kernel(const float* __restrict__ slots,
    const int* __restrict__ idx, const float* __restrict__ commit, float* __restrict__ out)
{
  int t = blockIdx.x * 256 + threadIdx.x;
  if (t < B_ * NS_ * D_) out[t] = slots[t];
  if (t < B_ * NS_) {
    float iv = (float)idx[t];
    out[1769472 + t] = iv;
    out[1769857 + t] = iv;
  }
  if (t == 0) out[1769856] = commit[0];
}

// ---------------------------------------------------------------------------
extern "C" void kernel_launch(void* const* d_in, const int* in_sizes, int n_in,
                              void* d_out, int out_size, void* d_ws, size_t ws_size,
                              hipStream_t stream)
{
  const float* inputs  = (const float*)d_in[0];
  const float* cond    = (const float*)d_in[1];
  const float* Wq      = (const float*)d_in[2];
  const float* Wk      = (const float*)d_in[3];
  const float* Wv      = (const float*)d_in[4];
  const float* w_ih    = (const float*)d_in[5];
  const float* w_hh    = (const float*)d_in[6];
  const float* b_ih    = (const float*)d_in[7];
  const float* b_hh    = (const float*)d_in[8];
  const float* ln_in_g = (const float*)d_in[9];
  const float* ln_in_b = (const float*)d_in[10];
  const float* ln_s_g  = (const float*)d_in[11];
  const float* ln_s_b  = (const float*)d_in[12];
  const float* ln_f_g  = (const float*)d_in[13];
  const float* ln_f_b  = (const float*)d_in[14];
  const float* W1      = (const float*)d_in[15];
  const float* b1      = (const float*)d_in[16];
  const float* W2      = (const float*)d_in[17];
  const float* b2      = (const float*)d_in[18];
  const float* A1      = (const float*)d_in[19];
  const float* B1m     = (const float*)d_in[20];
  const float* A2      = (const float*)d_in[21];
  const float* B2m     = (const float*)d_in[22];
  const float* codebook= (const float*)d_in[23];

  float* out = (float*)d_out;
  float* ws  = (float*)d_ws;

  // ---- region 0 (33.5M fslots): phase A = xhat_hl; loop = dots + scratch --
  unsigned short* xhat_hl = (unsigned short*)ws;
  float* dots    = ws;                                       // 12582912
  float* updpart = ws + 12582912;                            // 8*196608 = 1572864
  float* gpart   = ws + 14155776;                            // 3145728
  unsigned short* WqT  = (unsigned short*)(ws + 17301504);   // 512x1536 u16
  unsigned short* wihT = (unsigned short*)(ws + 17694720);   // 1536x1536 u16
  unsigned short* whhT = (unsigned short*)(ws + 18874368);   // 1536x1536 u16
  unsigned short* W1T  = (unsigned short*)(ws + 20054016);   // 2048x1536 u16
  unsigned short* W2T  = (unsigned short*)(ws + 21626880);   // 512x6144 u16
  unsigned short* s_hl    = (unsigned short*)(ws + 23199744);  // 384x1024
  unsigned short* slotshl = (unsigned short*)(ws + 23396352);  // 384x1024
  unsigned short* updhl   = (unsigned short*)(ws + 23592960);  // 384x1024
  unsigned short* h1hl    = (unsigned short*)(ws + 23789568);  // 384x8192 -> ends 25362432

  size_t off = 33554432;
  float* kbuf = ws + off; off += 33554432;
  float* vbuf = ws + off; off += 33554432;
  unsigned short* WkT = (unsigned short*)(ws + off); off += 393216;
  unsigned short* WvT = (unsigned short*)(ws + off); off += 393216;
  float* slots_cur = ws + off; off += BNSD_;
  float* slots_gru = ws + off; off += BNSD_;
  float* sbuf      = ws + off; off += BNSD_;
  float* qb        = ws + off; off += BNSD_;
  float* gib       = ws + off; off += B_ * NS_ * 3 * D_;
  float* ghb       = ws + off; off += B_ * NS_ * 3 * D_;
  float* h1b       = ws + off; off += B_ * NS_ * 4 * D_;
  float* vsumb     = ws + off; off += B_ * H_ * DH_;
  float* asumb     = ws + off; off += B_ * TT_;
  float* commitb   = ws + off; off += 1;
  int*   idxb      = (int*)(ws + off); off += B_ * NS_;

  // ---- phase A: LN(inputs)->hl, k/v MFMA, then weight prep in region 0 ----
  ln_hl_kernel<<<B_ * N_, 128, 0, stream>>>(inputs, ln_in_g, ln_in_b, xhat_hl);
  wtrans_g<<<dim3(8, 8), 256, 0, stream>>>(Wk, WkT, 512, 512);
  wtrans_g<<<dim3(8, 8), 256, 0, stream>>>(Wv, WvT, 512, 512);
  gemm_kv<<<dim3(4, 512), 256, 0, stream>>>(xhat_hl, WkT, kbuf);
  gemm_kv<<<dim3(4, 512), 256, 0, stream>>>(xhat_hl, WvT, vbuf);
  vsum_kernel<<<B_ * H_, 256, 0, stream>>>(vbuf, vsumb);
  // xhat region now dead -> safe to write weights/operands there
  wtrans_g<<<dim3(8, 8), 256, 0, stream>>>(Wq, WqT, 512, 512);
  wsplit_nm<<<3072, 256, 0, stream>>>(w_ih, wihT, 512, 1536 * 512);
  wsplit_nm<<<3072, 256, 0, stream>>>(w_hh, whhT, 512, 1536 * 512);
  wtrans_g<<<dim3(32, 8), 256, 0, stream>>>(W1, W1T, 512, 2048);
  wtrans_g<<<dim3(8, 32), 256, 0, stream>>>(W2, W2T, 2048, 512);
  f32tohl_kernel<<<768, 256, 0, stream>>>(cond, slots_cur, slotshl, BNSD_);

  // ---- phase B: 3 slot-attention iterations ----
  for (int it = 0; it < 3; ++it) {
    if (it > 0) {
      hipMemsetAsync(commitb, 0, sizeof(float), stream);
      vq_kernel<<<B_ * NS_, 256, 0, stream>>>(slots_cur, codebook, idxb, commitb);
    }
    ln_dual_kernel<<<B_ * NS_, 128, 0, stream>>>(slots_cur, ln_s_g, ln_s_b, sbuf, s_hl);
    // q = s @ Wq : N=512, K=512, Z=4, S=6
    gemm_sp<<<dim3(8, 3, 4), 256, 0, stream>>>(s_hl, WqT, gpart, 512, 512, 6);
    redep<false, false, false><<<768, 256, 0, stream>>>(gpart, nullptr, nullptr, qb, nullptr, 512, 4);
    dots_kernel<<<dim3(N_ / 64, B_ * H_), 256, 0, stream>>>(qb, kbuf, dots);
    softmax_kernel<<<dim3(N_ / 64, B_), 256, 0, stream>>>(
        dots, (it == 2) ? (out + (size_t)BNSD_) : nullptr);
    asum_kernel<<<B_ * TT_, 256, 0, stream>>>(dots, asumb);
    upd_part_kernel<<<dim3(B_ * H_, 8), 256, 0, stream>>>(dots, vbuf, updpart);
    upd_fin_kernel<<<BNSD_ / 256, 256, 0, stream>>>(updpart, vsumb, asumb, updhl);
    // gi = upd @ w_ih.T + b_ih : N=1536, K=512, Z=4, S=6
    gemm_sp<<<dim3(24, 3, 4), 256, 0, stream>>>(updhl, wihT, gpart, 1536, 512, 6);
    redep<true, false, false><<<2304, 256, 0, stream>>>(gpart, b_ih, nullptr, gib, nullptr, 1536, 4);
    // gh = slots @ w_hh.T + b_hh
    gemm_sp<<<dim3(24, 3, 4), 256, 0, stream>>>(slotshl, whhT, gpart, 1536, 512, 6);
    redep<true, false, false><<<2304, 256, 0, stream>>>(gpart, b_hh, nullptr, ghb, nullptr, 1536, 4);
    gru_kernel<<<BNSD_ / 256, 256, 0, stream>>>(gib, ghb, slots_cur, slots_gru);
    ln_dual_kernel<<<B_ * NS_, 128, 0, stream>>>(slots_gru, ln_f_g, ln_f_b, sbuf, s_hl);
    // h1 = s2 @ W1 + b1 : N=2048, K=512, Z=4, S=6
    gemm_sp<<<dim3(32, 3, 4), 256, 0, stream>>>(s_hl, W1T, gpart, 2048, 512, 6);
    redep<true, false, false><<<3072, 256, 0, stream>>>(gpart, b1, nullptr, h1b, nullptr, 2048, 4);
    if (it > 0)
      lora_kernel<false><<<B_ * NS_, 256, 0, stream>>>(sbuf, A1, B1m, idxb, h1b, D_, 4 * D_);
    reluhl_kernel<<<3072, 256, 0, stream>>>(h1b, h1hl);
    // out = relu(h1) @ W2 + b2 + slots_gru : N=512, K=2048, Z=8, S=12
    gemm_sp<<<dim3(8, 3, 8), 256, 0, stream>>>(h1hl, W2T, gpart, 512, 2048, 12);
    redep<true, true, true><<<768, 256, 0, stream>>>(gpart, b2, slots_gru, slots_cur, slotshl, 512, 8);
    if (it > 0)
      lora_kernel<true><<<B_ * NS_, 256, 0, stream>>>(h1b, A2, B2m, idxb, slots_cur, 4 * D_, D_);
    if (it == 1)   // refresh hl after lora2 (needed by next iter's gh GEMM)
      f32tohl_kernel<<<768, 256, 0, stream>>>(slots_cur, nullptr, slotshl, BNSD_);
  }

  finalize_kernel<<<BNSD_ / 256, 256, 0, stream>>>(slots_cur, idxb, commitb, out);
}